// Round 5
// baseline (167.052 us; speedup 1.0000x reference)
//
#include <hip/hip_runtime.h>
#include <hip/hip_bf16.h>
#include <stdint.h>

// Problem constants: B=4, CIN=COUT=256, H=W=64, 3x3, pad=1, stride=1, dil=1
#define KDIM 2304   // CIN * 9, GEMM K

typedef __bf16 bf16_t;
typedef bf16_t bf16x8 __attribute__((ext_vector_type(8)));
typedef float f32x4 __attribute__((ext_vector_type(4)));
typedef float f32x2 __attribute__((ext_vector_type(2)));

__device__ __forceinline__ float b2f_lo(uint32_t u) {
  union { uint32_t i; float f; } c; c.i = u << 16; return c.f;
}
__device__ __forceinline__ float b2f_hi(uint32_t u) {
  union { uint32_t i; float f; } c; c.i = u & 0xffff0000u; return c.f;
}
__device__ __forceinline__ uint32_t pk_bf16(float a, float b) {
  __hip_bfloat162 h = __float22bfloat162_rn(make_float2(a, b));
  union { __hip_bfloat162 h; uint32_t u; } c; c.h = h; return c.u;
}

// ---------------- merged prep kernel
// blocks [0,2048): x [4][256][64][64] f32 -> xt [4][64][64][256] bf16 (NHWC)
// blocks [2048,2304): one cout row each: weight -> wt2 fragment-linear bf16:
//   wt2[i(36)][slot(2048)][8], slot = strip*128 + kh*64 + lane,
//   element = w[row=strip*16+(lane&15)][cin=(i&3)*64+kh*32+(lane>>4)*8+e][tap=i>>2]
__global__ __launch_bounds__(256) void k_prep(const float* __restrict__ x,
                                              uint16_t* __restrict__ xt,
                                              const float* __restrict__ w,
                                              uint16_t* __restrict__ wt2) {
  int tid = threadIdx.x;
  if (blockIdx.x < 2048) {
    __shared__ float tile[32][65];
    int b = blockIdx.x >> 9;
    int cgrp = (blockIdx.x >> 6) & 7;
    int sgrp = blockIdx.x & 63;
    int c0 = cgrp << 5, s0 = sgrp << 6;
#pragma unroll
    for (int it = 0; it < 2; ++it) {
      int f = tid + it * 256;
      int rr = f >> 4, col = (f & 15) << 2;
      float4 v = *(const float4*)&x[((size_t)(b * 256 + c0 + rr)) * 4096 + s0 + col];
      tile[rr][col + 0] = v.x;
      tile[rr][col + 1] = v.y;
      tile[rr][col + 2] = v.z;
      tile[rr][col + 3] = v.w;
    }
    __syncthreads();
    int sp = tid >> 2, cg = tid & 3;
    uint4 o;
    o.x = pk_bf16(tile[cg * 8 + 0][sp], tile[cg * 8 + 1][sp]);
    o.y = pk_bf16(tile[cg * 8 + 2][sp], tile[cg * 8 + 3][sp]);
    o.z = pk_bf16(tile[cg * 8 + 4][sp], tile[cg * 8 + 5][sp]);
    o.w = pk_bf16(tile[cg * 8 + 6][sp], tile[cg * 8 + 7][sp]);
    *(uint4*)&xt[((size_t)b * 4096 + s0 + sp) * 256 + c0 + cg * 8] = o;
  } else {
    // one cout row per block: coalesced row load -> LDS, scatter 16B writes out
    __shared__ float wl[2304];
    int row = blockIdx.x - 2048;
    const float* wrow = w + (size_t)row * KDIM;
    for (int i2 = tid; i2 < 2304; i2 += 256) wl[i2] = wrow[i2];
    __syncthreads();
    int strip = row >> 4, r16 = row & 15;
    for (int c = tid; c < 288; c += 256) {   // c = tap*32 + w64*8 + kh*4 + seg
      int tap = c >> 5, rem = c & 31;
      int w64 = rem >> 3, kh = (rem >> 2) & 1, seg = rem & 3;
      int i = tap * 4 + w64;
      int cin0 = w64 * 64 + kh * 32 + seg * 8;
      int lanex = seg * 16 + r16;
      uint16_t* dst = wt2 + (size_t)i * 16384 + (size_t)(strip * 128 + kh * 64 + lanex) * 8;
      uint4 o;
      o.x = pk_bf16(wl[(cin0 + 0) * 9 + tap], wl[(cin0 + 1) * 9 + tap]);
      o.y = pk_bf16(wl[(cin0 + 2) * 9 + tap], wl[(cin0 + 3) * 9 + tap]);
      o.z = pk_bf16(wl[(cin0 + 4) * 9 + tap], wl[(cin0 + 5) * 9 + tap]);
      o.w = pk_bf16(wl[(cin0 + 6) * 9 + tap], wl[(cin0 + 7) * 9 + tap]);
      *(uint4*)dst = o;
    }
  }
}

// per-thread bilinear corner setup for one tap (full 64-position row, wo = p)
__device__ __forceinline__ void mk_corners(int tap, int p, int ho,
                                           const float* s_off, const float* s_msk,
                                           float cw[4], int cpo[4]) {
  int kh = tap / 3, kw = tap - kh * 3;
  float dy = s_off[(2 * tap) * 64 + p];
  float dx = s_off[(2 * tap + 1) * 64 + p];
  float mm = s_msk[tap * 64 + p];
  float sy = (float)(ho - 1 + kh) + dy;
  float sx = (float)(p - 1 + kw) + dx;
  float fy = floorf(sy), fx = floorf(sx);
  int y0 = (int)fy, x0 = (int)fx;
  float wy = sy - fy, wx = sx - fx;
#pragma unroll
  for (int cy = 0; cy < 2; ++cy) {
#pragma unroll
    for (int cx = 0; cx < 2; ++cx) {
      int y = y0 + cy, xx = x0 + cx;
      float wgt = (cy ? wy : 1.f - wy) * (cx ? wx : 1.f - wx) * mm;
      bool v = ((unsigned)y < 64u) && ((unsigned)xx < 64u);
      wgt = v ? wgt : 0.f;
      int yc = min(max(y, 0), 63), xc = min(max(xx, 0), 63);
      cw[cy * 2 + cx] = wgt;
      cpo[cy * 2 + cx] = ((yc << 6) + xc) * 256;
    }
  }
}

// ---------------- FUSED deform-im2col + GEMM, register-A, distance-2 prefetch
// Block: 1024 thr = 16 waves (4/SIMD), grid 256 = 1 block/CU. BM=256, BN=64.
// Sync primitive: __syncthreads() ONLY (r3-verified protocol; r4's raw-barrier
// counted-vmcnt pipeline was run-to-run nondeterministic -> reverted).
// Scheduling win kept from r4: BODY(i) issues dnv(i+2) gathers + AF(i+1)
// weight loads at the TOP; they stay in flight across ds_read+MFMA+blend
// (~600-800 cy) and are force-retired by the barrier's vmcnt(0) drain at the
// END of the body -- so the blend in body i+1 reads resident registers.
// Register deps are compiler-waitcnt-protected; Bs RAW/WAR edges are
// guaranteed by __syncthreads' full drain. No inline asm anywhere.
__global__ __launch_bounds__(1024, 4) void k_fused(const uint16_t* __restrict__ xt,
                                                   const uint16_t* __restrict__ wt2,
                                                   const float* __restrict__ off,
                                                   const float* __restrict__ msk,
                                                   const float* __restrict__ bias,
                                                   float* __restrict__ out) {
  __shared__ __align__(16) uint16_t Bs[2][64][64];  // 16 KB [buf][pos][k], swizzled
  __shared__ float s_off[18 * 64];
  __shared__ float s_msk[9 * 64];

  int tid = threadIdx.x;
  int swz = ((int)blockIdx.x & 7) * 32 + ((int)blockIdx.x >> 3);
  int b = swz >> 6, ho = swz & 63;

  const float* offb = off + (size_t)b * 18 * 4096 + ho * 64;
  for (int i = tid; i < 18 * 64; i += 1024)
    s_off[i] = offb[(size_t)(i >> 6) * 4096 + (i & 63)];
  const float* mskb = msk + (size_t)b * 9 * 4096 + ho * 64;
  for (int i = tid; i < 9 * 64; i += 1024)
    s_msk[i] = mskb[(size_t)(i >> 6) * 4096 + (i & 63)];

  int lane = tid & 63, strip = tid >> 6;    // 16 waves = 16 M-strips of 16 rows
  int q = lane >> 4, r = lane & 15;
  int p = tid >> 4, cg = tid & 15;          // B gather: position p, chunk cg
  const uint16_t* xtb = xt + (size_t)b * 4096 * 256 + cg * 4;
  int bcol = (((cg >> 1) ^ (p & 7)) << 3) + ((cg & 1) << 2);  // swizzled u16 col

  f32x4 acc[4];
#pragma unroll
  for (int ni = 0; ni < 4; ++ni) acc[ni] = f32x4{0.f, 0.f, 0.f, 0.f};

  __syncthreads();  // off/msk staged

  float cwA[4], cwB[4];
  int cpoA[4], cpoB[4];
  uint2 dnvE[4], dnvO[4];       // dnv(j) lives in set j&1 (E=even)
  bf16x8 AFE[2], AFO[2];        // AF(j) lives in set j&1

  int c0 = (q ^ (r & 7)) << 3;  // swizzled u16 col, kh=0 fragment
  int c1 = c0 ^ 32;             // kh=1

  // ---- prologue: issue dnv(0), dnv(1), AF(0); blend(0) -> Bs[0]
  mk_corners(0, p, ho, s_off, s_msk, cwA, cpoA);
#pragma unroll
  for (int c = 0; c < 4; ++c) dnvE[c] = *(const uint2*)(xtb + cpoA[c]);        // dnv(0)
#pragma unroll
  for (int c = 0; c < 4; ++c) dnvO[c] = *(const uint2*)(xtb + cpoA[c] + 64);   // dnv(1)
  {
    const uint16_t* wp = wt2 + strip * 1024 + lane * 8;                        // AF(0)
    AFE[0] = *(const bf16x8*)(wp);
    AFE[1] = *(const bf16x8*)(wp + 512);
  }
  {
    f32x2 a0 = {0.f, 0.f}, a1 = {0.f, 0.f};
#pragma unroll
    for (int c = 0; c < 4; ++c) {
      f32x2 wc = {cwA[c], cwA[c]};
      a0 += wc * f32x2{b2f_lo(dnvE[c].x), b2f_hi(dnvE[c].x)};
      a1 += wc * f32x2{b2f_lo(dnvE[c].y), b2f_hi(dnvE[c].y)};
    }
    uint2 o;
    o.x = pk_bf16(a0.x, a0.y);
    o.y = pk_bf16(a1.x, a1.y);
    *(uint2*)&Bs[0][p][bcol] = o;
  }
  __syncthreads();
  // entering BODY(0): dnv(1) and AF(0) already resident (barrier drained them)

#define BODY(I, AFC, AFN, DNB, DNI, CWB, CWI, CPOI, DOMK, DODNV, DOAF, DOBL)    \
  {                                                                             \
    if (DOMK) mk_corners(((I) + 2) >> 2, p, ho, s_off, s_msk, CWI, CPOI);       \
    if (DODNV) {                                                                \
      const int chw = (((I) + 2) & 3) << 6;                                     \
      DNI[0] = *(const uint2*)(xtb + CPOI[0] + chw);                            \
      DNI[1] = *(const uint2*)(xtb + CPOI[1] + chw);                            \
      DNI[2] = *(const uint2*)(xtb + CPOI[2] + chw);                            \
      DNI[3] = *(const uint2*)(xtb + CPOI[3] + chw);                            \
    }                                                                           \
    if (DOAF) {                                                                 \
      const uint16_t* wp = wt2 + (size_t)((I) + 1) * 16384 + strip * 1024 + lane * 8; \
      AFN[0] = *(const bf16x8*)(wp);                                            \
      AFN[1] = *(const bf16x8*)(wp + 512);                                      \
    }                                                                           \
    {                                                                           \
      const uint16_t* bsrow = &Bs[(I) & 1][0][0];                               \
      bf16x8 b00 = *(const bf16x8*)(bsrow + (r) * 64 + c0);                     \
      bf16x8 b01 = *(const bf16x8*)(bsrow + (r) * 64 + c1);                     \
      bf16x8 b10 = *(const bf16x8*)(bsrow + (16 + r) * 64 + c0);                \
      bf16x8 b11 = *(const bf16x8*)(bsrow + (16 + r) * 64 + c1);                \
      bf16x8 b20 = *(const bf16x8*)(bsrow + (32 + r) * 64 + c0);                \
      bf16x8 b21 = *(const bf16x8*)(bsrow + (32 + r) * 64 + c1);                \
      bf16x8 b30 = *(const bf16x8*)(bsrow + (48 + r) * 64 + c0);                \
      bf16x8 b31 = *(const bf16x8*)(bsrow + (48 + r) * 64 + c1);                \
      __builtin_amdgcn_s_setprio(1);                                            \
      acc[0] = __builtin_amdgcn_mfma_f32_16x16x32_bf16(AFC[0], b00, acc[0], 0, 0, 0); \
      acc[1] = __builtin_amdgcn_mfma_f32_16x16x32_bf16(AFC[0], b10, acc[1], 0, 0, 0); \
      acc[2] = __builtin_amdgcn_mfma_f32_16x16x32_bf16(AFC[0], b20, acc[2], 0, 0, 0); \
      acc[3] = __builtin_amdgcn_mfma_f32_16x16x32_bf16(AFC[0], b30, acc[3], 0, 0, 0); \
      acc[0] = __builtin_amdgcn_mfma_f32_16x16x32_bf16(AFC[1], b01, acc[0], 0, 0, 0); \
      acc[1] = __builtin_amdgcn_mfma_f32_16x16x32_bf16(AFC[1], b11, acc[1], 0, 0, 0); \
      acc[2] = __builtin_amdgcn_mfma_f32_16x16x32_bf16(AFC[1], b21, acc[2], 0, 0, 0); \
      acc[3] = __builtin_amdgcn_mfma_f32_16x16x32_bf16(AFC[1], b31, acc[3], 0, 0, 0); \
      __builtin_amdgcn_s_setprio(0);                                            \
    }                                                                           \
    if (DOBL) {                                                                 \
      f32x2 a0 = {0.f, 0.f}, a1 = {0.f, 0.f};                                   \
      _Pragma("unroll")                                                         \
      for (int c = 0; c < 4; ++c) {                                             \
        f32x2 wc = {CWB[c], CWB[c]};                                            \
        a0 += wc * f32x2{b2f_lo(DNB[c].x), b2f_hi(DNB[c].x)};                   \
        a1 += wc * f32x2{b2f_lo(DNB[c].y), b2f_hi(DNB[c].y)};                   \
      }                                                                         \
      uint2 o;                                                                  \
      o.x = pk_bf16(a0.x, a0.y);                                                \
      o.y = pk_bf16(a1.x, a1.y);                                                \
      *(uint2*)&Bs[((I) + 1) & 1][p][bcol] = o;                                 \
    }                                                                           \
    __syncthreads();                                                            \
  }

  // main loop: i = 0..31 (period-8 tap-slot pattern, all set choices static)
#pragma unroll 1
  for (int ii = 0; ii < 4; ++ii) {
    int i0 = 8 * ii;
    BODY(i0 + 0, AFE, AFO, dnvO, dnvE, cwA, cwA, cpoA, 0, 1, 1, 1)
    BODY(i0 + 1, AFO, AFE, dnvE, dnvO, cwA, cwA, cpoA, 0, 1, 1, 1)
    BODY(i0 + 2, AFE, AFO, dnvO, dnvE, cwA, cwB, cpoB, 1, 1, 1, 1)
    BODY(i0 + 3, AFO, AFE, dnvE, dnvO, cwB, cwB, cpoB, 0, 1, 1, 1)
    BODY(i0 + 4, AFE, AFO, dnvO, dnvE, cwB, cwB, cpoB, 0, 1, 1, 1)
    BODY(i0 + 5, AFO, AFE, dnvE, dnvO, cwB, cwB, cpoB, 0, 1, 1, 1)
    BODY(i0 + 6, AFE, AFO, dnvO, dnvE, cwB, cwA, cpoA, 1, 1, 1, 1)
    BODY(i0 + 7, AFO, AFE, dnvE, dnvO, cwA, cwA, cpoA, 0, 1, 1, 1)
  }
  // tail: i = 32..35 (tap 8; slot A)
  BODY(32, AFE, AFO, dnvO, dnvE, cwA, cwA, cpoA, 0, 1, 1, 1)
  BODY(33, AFO, AFE, dnvE, dnvO, cwA, cwA, cpoA, 0, 1, 1, 1)
  BODY(34, AFE, AFO, dnvO, dnvE, cwA, cwA, cpoA, 0, 0, 1, 1)
  BODY(35, AFO, AFE, dnvE, dnvO, cwA, cwA, cpoA, 0, 0, 0, 0)
#undef BODY

  // epilogue: C/D layout col(n) = lane&15 = r, row(m) = q*4 + j
#pragma unroll
  for (int j = 0; j < 4; ++j) {
    int m = strip * 16 + q * 4 + j;
    float bv = bias[m];
#pragma unroll
    for (int ni = 0; ni < 4; ++ni) {
      out[((size_t)(b * 256 + m)) * 4096 + ho * 64 + ni * 16 + r] = acc[ni][j] + bv;
    }
  }
}

extern "C" void kernel_launch(void* const* d_in, const int* in_sizes, int n_in,
                              void* d_out, int out_size, void* d_ws, size_t ws_size,
                              hipStream_t stream) {
  (void)in_sizes; (void)n_in; (void)out_size; (void)ws_size;
  const float* x      = (const float*)d_in[0];  // [4][256][64][64]
  const float* offset = (const float*)d_in[1];  // [4][18][64][64]
  const float* mask   = (const float*)d_in[2];  // [4][9][64][64]
  const float* weight = (const float*)d_in[3];  // [256][256][3][3]
  const float* bias   = (const float*)d_in[4];  // [256]
  float* out = (float*)d_out;                   // [4][256][64][64]

  uint8_t* ws = (uint8_t*)d_ws;
  uint16_t* xt  = (uint16_t*)ws;                // 8,388,608 B : NHWC bf16
  uint16_t* wt2 = (uint16_t*)(ws + 8388608);    // 1,179,648 B : fragment-linear

  k_prep<<<dim3(2304), 256, 0, stream>>>(x, xt, weight, wt2);
  k_fused<<<dim3(256), 1024, 0, stream>>>(xt, wt2, offset, mask, bias, out);
}

// Round 6
// 130.726 us; speedup vs baseline: 1.2779x; 1.2779x over previous
//
#include <hip/hip_runtime.h>
#include <hip/hip_bf16.h>
#include <stdint.h>

// Problem constants: B=4, CIN=COUT=256, H=W=64, 3x3, pad=1, stride=1, dil=1
#define KDIM 2304   // CIN * 9, GEMM K

typedef __bf16 bf16_t;
typedef bf16_t bf16x8 __attribute__((ext_vector_type(8)));
typedef float f32x4 __attribute__((ext_vector_type(4)));
typedef float f32x2 __attribute__((ext_vector_type(2)));

__device__ __forceinline__ float b2f_lo(uint32_t u) {
  union { uint32_t i; float f; } c; c.i = u << 16; return c.f;
}
__device__ __forceinline__ float b2f_hi(uint32_t u) {
  union { uint32_t i; float f; } c; c.i = u & 0xffff0000u; return c.f;
}
__device__ __forceinline__ uint32_t pk_bf16(float a, float b) {
  __hip_bfloat162 h = __float22bfloat162_rn(make_float2(a, b));
  union { __hip_bfloat162 h; uint32_t u; } c; c.h = h; return c.u;
}

// ---------------- merged prep kernel (unchanged from r5 — verified)
// blocks [0,2048): x [4][256][64][64] f32 -> xt [4][64][64][256] bf16 (NHWC)
// blocks [2048,2304): one cout row each: weight -> wt2 fragment-linear bf16:
//   wt2[i(36)][slot(2048)][8], slot = strip*128 + kh*64 + lane,
//   element = w[row=strip*16+(lane&15)][cin=(i&3)*64+kh*32+(lane>>4)*8+e][tap=i>>2]
//   note strip = wm*2 + mi, so slot = wm*256 + mi*128 + kh*64 + lane.
__global__ __launch_bounds__(256) void k_prep(const float* __restrict__ x,
                                              uint16_t* __restrict__ xt,
                                              const float* __restrict__ w,
                                              uint16_t* __restrict__ wt2) {
  int tid = threadIdx.x;
  if (blockIdx.x < 2048) {
    __shared__ float tile[32][65];
    int b = blockIdx.x >> 9;
    int cgrp = (blockIdx.x >> 6) & 7;
    int sgrp = blockIdx.x & 63;
    int c0 = cgrp << 5, s0 = sgrp << 6;
#pragma unroll
    for (int it = 0; it < 2; ++it) {
      int f = tid + it * 256;
      int rr = f >> 4, col = (f & 15) << 2;
      float4 v = *(const float4*)&x[((size_t)(b * 256 + c0 + rr)) * 4096 + s0 + col];
      tile[rr][col + 0] = v.x;
      tile[rr][col + 1] = v.y;
      tile[rr][col + 2] = v.z;
      tile[rr][col + 3] = v.w;
    }
    __syncthreads();
    int sp = tid >> 2, cg = tid & 3;
    uint4 o;
    o.x = pk_bf16(tile[cg * 8 + 0][sp], tile[cg * 8 + 1][sp]);
    o.y = pk_bf16(tile[cg * 8 + 2][sp], tile[cg * 8 + 3][sp]);
    o.z = pk_bf16(tile[cg * 8 + 4][sp], tile[cg * 8 + 5][sp]);
    o.w = pk_bf16(tile[cg * 8 + 6][sp], tile[cg * 8 + 7][sp]);
    *(uint4*)&xt[((size_t)b * 4096 + s0 + sp) * 256 + c0 + cg * 8] = o;
  } else {
    // one cout row per block: coalesced row load -> LDS, scatter 16B writes out
    __shared__ float wl[2304];
    int row = blockIdx.x - 2048;
    const float* wrow = w + (size_t)row * KDIM;
    for (int i2 = tid; i2 < 2304; i2 += 256) wl[i2] = wrow[i2];
    __syncthreads();
    int strip = row >> 4, r16 = row & 15;
    for (int c = tid; c < 288; c += 256) {   // c = tap*32 + w64*8 + kh*4 + seg
      int tap = c >> 5, rem = c & 31;
      int w64 = rem >> 3, kh = (rem >> 2) & 1, seg = rem & 3;
      int i = tap * 4 + w64;
      int cin0 = w64 * 64 + kh * 32 + seg * 8;
      int lanex = seg * 16 + r16;
      uint16_t* dst = wt2 + (size_t)i * 16384 + (size_t)(strip * 128 + kh * 64 + lanex) * 8;
      uint4 o;
      o.x = pk_bf16(wl[(cin0 + 0) * 9 + tap], wl[(cin0 + 1) * 9 + tap]);
      o.y = pk_bf16(wl[(cin0 + 2) * 9 + tap], wl[(cin0 + 3) * 9 + tap]);
      o.z = pk_bf16(wl[(cin0 + 4) * 9 + tap], wl[(cin0 + 5) * 9 + tap]);
      o.w = pk_bf16(wl[(cin0 + 6) * 9 + tap], wl[(cin0 + 7) * 9 + tap]);
      *(uint4*)dst = o;
    }
  }
}

// per-thread bilinear corner setup for one tap (full 64-position row, wo = p)
__device__ __forceinline__ void mk_corners(int tap, int p, int ho,
                                           const float* s_off, const float* s_msk,
                                           float cw[4], int cpo[4]) {
  int kh = tap / 3, kw = tap - kh * 3;
  float dy = s_off[(2 * tap) * 64 + p];
  float dx = s_off[(2 * tap + 1) * 64 + p];
  float mm = s_msk[tap * 64 + p];
  float sy = (float)(ho - 1 + kh) + dy;
  float sx = (float)(p - 1 + kw) + dx;
  float fy = floorf(sy), fx = floorf(sx);
  int y0 = (int)fy, x0 = (int)fx;
  float wy = sy - fy, wx = sx - fx;
#pragma unroll
  for (int cy = 0; cy < 2; ++cy) {
#pragma unroll
    for (int cx = 0; cx < 2; ++cx) {
      int y = y0 + cy, xx = x0 + cx;
      float wgt = (cy ? wy : 1.f - wy) * (cx ? wx : 1.f - wx) * mm;
      bool v = ((unsigned)y < 64u) && ((unsigned)xx < 64u);
      wgt = v ? wgt : 0.f;
      int yc = min(max(y, 0), 63), xc = min(max(xx, 0), 63);
      cw[cy * 2 + cx] = wgt;
      cpo[cy * 2 + cx] = ((yc << 6) + xc) * 256;
    }
  }
}

// ---------------- FUSED deform-im2col + GEMM, register-A, 32x32 wave tiles
// Block: 1024 thr = 16 waves (4/SIMD), grid 256 = 1 block/CU. BM=256, BN=64.
// Wave tiling: 8 wm x 2 wn, each wave owns a 32x32 output tile. This HALVES
// LDS read traffic vs r3's 16x64 strips (each wave reads 4KB not 8KB of B per
// body: 64KB/body/CU vs 128KB, at ~85B/cy the dominant r3 cost), and A stays
// 4KB/wave from L1-broadcast wt2 (wn-pairs read identical fragments).
// Sync/dataflow protocol is EXACTLY r3's verified one: __syncthreads only,
// distance-1 dnv (load top of body, blend bottom of same body), AF(i+1)
// double-buffered. Peak regs ~100 < 128 cap -> no scratch (r5's 178MB
// WRITE_SIZE spill regression removed). Accumulation order per output
// unchanged -> bit-identical result.
__global__ __launch_bounds__(1024, 4) void k_fused(const uint16_t* __restrict__ xt,
                                                   const uint16_t* __restrict__ wt2,
                                                   const float* __restrict__ off,
                                                   const float* __restrict__ msk,
                                                   const float* __restrict__ bias,
                                                   float* __restrict__ out) {
  __shared__ __align__(16) uint16_t Bs[2][64][64];  // 16 KB [buf][pos][k], swizzled
  __shared__ float s_off[18 * 64];
  __shared__ float s_msk[9 * 64];

  int tid = threadIdx.x;
  int swz = ((int)blockIdx.x & 7) * 32 + ((int)blockIdx.x >> 3);
  int b = swz >> 6, ho = swz & 63;

  const float* offb = off + (size_t)b * 18 * 4096 + ho * 64;
  for (int i = tid; i < 18 * 64; i += 1024)
    s_off[i] = offb[(size_t)(i >> 6) * 4096 + (i & 63)];
  const float* mskb = msk + (size_t)b * 9 * 4096 + ho * 64;
  for (int i = tid; i < 9 * 64; i += 1024)
    s_msk[i] = mskb[(size_t)(i >> 6) * 4096 + (i & 63)];

  int lane = tid & 63, wv = tid >> 6;
  int wm = wv >> 1, wn = wv & 1;            // 8 M-tiles x 2 N-tiles of 32x32
  int q = lane >> 4, r = lane & 15;
  int p = tid >> 4, cg = tid & 15;          // B gather: position p, chunk cg
  const uint16_t* xtb = xt + (size_t)b * 4096 * 256 + cg * 4;
  int bcol = (((cg >> 1) ^ (p & 7)) << 3) + ((cg & 1) << 2);  // swizzled u16 col

  f32x4 acc[2][2];
#pragma unroll
  for (int mi = 0; mi < 2; ++mi)
#pragma unroll
    for (int ni = 0; ni < 2; ++ni) acc[mi][ni] = f32x4{0.f, 0.f, 0.f, 0.f};

  __syncthreads();  // off/msk staged

  float cw[4];
  int cpo[4];
  uint2 dnv[4];
  bf16x8 AFA[2][2], AFB[2][2];   // [mi][kh]

  int c0 = (q ^ (r & 7)) << 3;   // swizzled u16 col, kh=0 fragment
  int c1 = c0 ^ 32;              // kh=1
  int rb0 = (wn * 32 + r) * 64;  // ni=0 row offset (u16); ni=1 adds 1024

  // ---- prologue: issue dnv(0) + AF(0); blend(0) -> Bs[0]
  mk_corners(0, p, ho, s_off, s_msk, cw, cpo);
#pragma unroll
  for (int c = 0; c < 4; ++c) dnv[c] = *(const uint2*)(xtb + cpo[c]);
  {
    const uint16_t* wp = wt2 + wm * 2048 + lane * 8;
    AFA[0][0] = *(const bf16x8*)(wp);
    AFA[0][1] = *(const bf16x8*)(wp + 512);
    AFA[1][0] = *(const bf16x8*)(wp + 1024);
    AFA[1][1] = *(const bf16x8*)(wp + 1536);
  }
  {
    f32x2 a0 = {0.f, 0.f}, a1 = {0.f, 0.f};
#pragma unroll
    for (int c = 0; c < 4; ++c) {
      f32x2 wc = {cw[c], cw[c]};
      a0 += wc * f32x2{b2f_lo(dnv[c].x), b2f_hi(dnv[c].x)};
      a1 += wc * f32x2{b2f_lo(dnv[c].y), b2f_hi(dnv[c].y)};
    }
    uint2 o;
    o.x = pk_bf16(a0.x, a0.y);
    o.y = pk_bf16(a1.x, a1.y);
    *(uint2*)&Bs[0][p][bcol] = o;
  }
  __syncthreads();

#define BODY(I, AFC, AFN, DOMK, DODNV, DOAF, DOBL)                              \
  {                                                                             \
    if (DOMK) mk_corners(((I) + 1) >> 2, p, ho, s_off, s_msk, cw, cpo);         \
    if (DODNV) {                                                                \
      const int chw = (((I) + 1) & 3) << 6;                                     \
      dnv[0] = *(const uint2*)(xtb + cpo[0] + chw);                             \
      dnv[1] = *(const uint2*)(xtb + cpo[1] + chw);                             \
      dnv[2] = *(const uint2*)(xtb + cpo[2] + chw);                             \
      dnv[3] = *(const uint2*)(xtb + cpo[3] + chw);                             \
    }                                                                           \
    if (DOAF) {                                                                 \
      const uint16_t* wp = wt2 + (size_t)((I) + 1) * 16384 + wm * 2048 + lane * 8; \
      AFN[0][0] = *(const bf16x8*)(wp);                                         \
      AFN[0][1] = *(const bf16x8*)(wp + 512);                                   \
      AFN[1][0] = *(const bf16x8*)(wp + 1024);                                  \
      AFN[1][1] = *(const bf16x8*)(wp + 1536);                                  \
    }                                                                           \
    {                                                                           \
      const uint16_t* bsrow = &Bs[(I) & 1][0][0];                               \
      bf16x8 b00 = *(const bf16x8*)(bsrow + rb0 + c0);          /* ni=0 kh=0 */ \
      bf16x8 b01 = *(const bf16x8*)(bsrow + rb0 + c1);          /* ni=0 kh=1 */ \
      bf16x8 b10 = *(const bf16x8*)(bsrow + rb0 + 1024 + c0);   /* ni=1 kh=0 */ \
      bf16x8 b11 = *(const bf16x8*)(bsrow + rb0 + 1024 + c1);   /* ni=1 kh=1 */ \
      __builtin_amdgcn_s_setprio(1);                                            \
      acc[0][0] = __builtin_amdgcn_mfma_f32_16x16x32_bf16(AFC[0][0], b00, acc[0][0], 0, 0, 0); \
      acc[0][1] = __builtin_amdgcn_mfma_f32_16x16x32_bf16(AFC[0][0], b10, acc[0][1], 0, 0, 0); \
      acc[1][0] = __builtin_amdgcn_mfma_f32_16x16x32_bf16(AFC[1][0], b00, acc[1][0], 0, 0, 0); \
      acc[1][1] = __builtin_amdgcn_mfma_f32_16x16x32_bf16(AFC[1][0], b10, acc[1][1], 0, 0, 0); \
      acc[0][0] = __builtin_amdgcn_mfma_f32_16x16x32_bf16(AFC[0][1], b01, acc[0][0], 0, 0, 0); \
      acc[0][1] = __builtin_amdgcn_mfma_f32_16x16x32_bf16(AFC[0][1], b11, acc[0][1], 0, 0, 0); \
      acc[1][0] = __builtin_amdgcn_mfma_f32_16x16x32_bf16(AFC[1][1], b01, acc[1][0], 0, 0, 0); \
      acc[1][1] = __builtin_amdgcn_mfma_f32_16x16x32_bf16(AFC[1][1], b11, acc[1][1], 0, 0, 0); \
      __builtin_amdgcn_s_setprio(0);                                            \
    }                                                                           \
    if (DOBL) {                                                                 \
      f32x2 a0 = {0.f, 0.f}, a1 = {0.f, 0.f};                                   \
      _Pragma("unroll")                                                         \
      for (int c = 0; c < 4; ++c) {                                             \
        f32x2 wc = {cw[c], cw[c]};                                              \
        a0 += wc * f32x2{b2f_lo(dnv[c].x), b2f_hi(dnv[c].x)};                   \
        a1 += wc * f32x2{b2f_lo(dnv[c].y), b2f_hi(dnv[c].y)};                   \
      }                                                                         \
      uint2 o;                                                                  \
      o.x = pk_bf16(a0.x, a0.y);                                                \
      o.y = pk_bf16(a1.x, a1.y);                                                \
      *(uint2*)&Bs[((I) + 1) & 1][p][bcol] = o;                                 \
    }                                                                           \
    __syncthreads();                                                            \
  }

  // main loop: i = 0..31; mk_corners fires when (i+1)%4 == 0 (group slot +3)
#pragma unroll 1
  for (int ii = 0; ii < 8; ++ii) {
    int i0 = 4 * ii;
    BODY(i0 + 0, AFA, AFB, 0, 1, 1, 1)
    BODY(i0 + 1, AFB, AFA, 0, 1, 1, 1)
    BODY(i0 + 2, AFA, AFB, 0, 1, 1, 1)
    BODY(i0 + 3, AFB, AFA, 1, 1, 1, 1)
  }
  // tail: i = 32..35 (tap 8)
  BODY(32, AFA, AFB, 0, 1, 1, 1)
  BODY(33, AFB, AFA, 0, 1, 1, 1)
  BODY(34, AFA, AFB, 0, 1, 1, 1)
  BODY(35, AFB, AFA, 0, 0, 0, 0)
#undef BODY

  // epilogue: C/D layout col(n) = lane&15 = r, row(m) = q*4 + j
#pragma unroll
  for (int mi = 0; mi < 2; ++mi) {
#pragma unroll
    for (int j = 0; j < 4; ++j) {
      int m = wm * 32 + mi * 16 + q * 4 + j;
      float bv = bias[m];
#pragma unroll
      for (int ni = 0; ni < 2; ++ni) {
        int wog = wn * 32 + ni * 16 + r;
        out[((size_t)(b * 256 + m)) * 4096 + ho * 64 + wog] = acc[mi][ni][j] + bv;
      }
    }
  }
}

extern "C" void kernel_launch(void* const* d_in, const int* in_sizes, int n_in,
                              void* d_out, int out_size, void* d_ws, size_t ws_size,
                              hipStream_t stream) {
  (void)in_sizes; (void)n_in; (void)out_size; (void)ws_size;
  const float* x      = (const float*)d_in[0];  // [4][256][64][64]
  const float* offset = (const float*)d_in[1];  // [4][18][64][64]
  const float* mask   = (const float*)d_in[2];  // [4][9][64][64]
  const float* weight = (const float*)d_in[3];  // [256][256][3][3]
  const float* bias   = (const float*)d_in[4];  // [256]
  float* out = (float*)d_out;                   // [4][256][64][64]

  uint8_t* ws = (uint8_t*)d_ws;
  uint16_t* xt  = (uint16_t*)ws;                // 8,388,608 B : NHWC bf16
  uint16_t* wt2 = (uint16_t*)(ws + 8388608);    // 1,179,648 B : fragment-linear

  k_prep<<<dim3(2304), 256, 0, stream>>>(x, xt, weight, wt2);
  k_fused<<<dim3(256), 1024, 0, stream>>>(xt, wt2, offset, mask, bias, out);
}

// Round 7
// 128.515 us; speedup vs baseline: 1.2999x; 1.0172x over previous
//
#include <hip/hip_runtime.h>
#include <hip/hip_bf16.h>
#include <stdint.h>

// Problem constants: B=4, CIN=COUT=256, H=W=64, 3x3, pad=1, stride=1, dil=1
#define KDIM 2304   // CIN * 9, GEMM K

typedef __bf16 bf16_t;
typedef bf16_t bf16x8 __attribute__((ext_vector_type(8)));
typedef float f32x4 __attribute__((ext_vector_type(4)));
typedef float f32x2 __attribute__((ext_vector_type(2)));

__device__ __forceinline__ float b2f_lo(uint32_t u) {
  union { uint32_t i; float f; } c; c.i = u << 16; return c.f;
}
__device__ __forceinline__ float b2f_hi(uint32_t u) {
  union { uint32_t i; float f; } c; c.i = u & 0xffff0000u; return c.f;
}
__device__ __forceinline__ uint32_t pk_bf16(float a, float b) {
  __hip_bfloat162 h = __float22bfloat162_rn(make_float2(a, b));
  union { __hip_bfloat162 h; uint32_t u; } c; c.h = h; return c.u;
}

// ---------------- merged prep kernel (unchanged from r6 — verified)
// blocks [0,2048): x [4][256][64][64] f32 -> xt [4][64][64][256] bf16 (NHWC)
// blocks [2048,2304): one cout row each: weight -> wt2 fragment-linear bf16:
//   wt2[i(36)][slot(2048)][8], slot = strip*128 + kh*64 + lane,
//   element = w[row=strip*16+(lane&15)][cin=(i&3)*64+kh*32+(lane>>4)*8+e][tap=i>>2]
__global__ __launch_bounds__(256) void k_prep(const float* __restrict__ x,
                                              uint16_t* __restrict__ xt,
                                              const float* __restrict__ w,
                                              uint16_t* __restrict__ wt2) {
  int tid = threadIdx.x;
  if (blockIdx.x < 2048) {
    __shared__ float tile[32][65];
    int b = blockIdx.x >> 9;
    int cgrp = (blockIdx.x >> 6) & 7;
    int sgrp = blockIdx.x & 63;
    int c0 = cgrp << 5, s0 = sgrp << 6;
#pragma unroll
    for (int it = 0; it < 2; ++it) {
      int f = tid + it * 256;
      int rr = f >> 4, col = (f & 15) << 2;
      float4 v = *(const float4*)&x[((size_t)(b * 256 + c0 + rr)) * 4096 + s0 + col];
      tile[rr][col + 0] = v.x;
      tile[rr][col + 1] = v.y;
      tile[rr][col + 2] = v.z;
      tile[rr][col + 3] = v.w;
    }
    __syncthreads();
    int sp = tid >> 2, cg = tid & 3;
    uint4 o;
    o.x = pk_bf16(tile[cg * 8 + 0][sp], tile[cg * 8 + 1][sp]);
    o.y = pk_bf16(tile[cg * 8 + 2][sp], tile[cg * 8 + 3][sp]);
    o.z = pk_bf16(tile[cg * 8 + 4][sp], tile[cg * 8 + 5][sp]);
    o.w = pk_bf16(tile[cg * 8 + 6][sp], tile[cg * 8 + 7][sp]);
    *(uint4*)&xt[((size_t)b * 4096 + s0 + sp) * 256 + c0 + cg * 8] = o;
  } else {
    // one cout row per block: coalesced row load -> LDS, scatter 16B writes out
    __shared__ float wl[2304];
    int row = blockIdx.x - 2048;
    const float* wrow = w + (size_t)row * KDIM;
    for (int i2 = tid; i2 < 2304; i2 += 256) wl[i2] = wrow[i2];
    __syncthreads();
    int strip = row >> 4, r16 = row & 15;
    for (int c = tid; c < 288; c += 256) {   // c = tap*32 + w64*8 + kh*4 + seg
      int tap = c >> 5, rem = c & 31;
      int w64 = rem >> 3, kh = (rem >> 2) & 1, seg = rem & 3;
      int i = tap * 4 + w64;
      int cin0 = w64 * 64 + kh * 32 + seg * 8;
      int lanex = seg * 16 + r16;
      uint16_t* dst = wt2 + (size_t)i * 16384 + (size_t)(strip * 128 + kh * 64 + lanex) * 8;
      uint4 o;
      o.x = pk_bf16(wl[(cin0 + 0) * 9 + tap], wl[(cin0 + 1) * 9 + tap]);
      o.y = pk_bf16(wl[(cin0 + 2) * 9 + tap], wl[(cin0 + 3) * 9 + tap]);
      o.z = pk_bf16(wl[(cin0 + 4) * 9 + tap], wl[(cin0 + 5) * 9 + tap]);
      o.w = pk_bf16(wl[(cin0 + 6) * 9 + tap], wl[(cin0 + 7) * 9 + tap]);
      *(uint4*)dst = o;
    }
  }
}

// per-thread bilinear corner setup for one tap (full 64-position row, wo = p)
__device__ __forceinline__ void mk_corners(int tap, int p, int ho,
                                           const float* s_off, const float* s_msk,
                                           float cw[4], int cpo[4]) {
  int kh = tap / 3, kw = tap - kh * 3;
  float dy = s_off[(2 * tap) * 64 + p];
  float dx = s_off[(2 * tap + 1) * 64 + p];
  float mm = s_msk[tap * 64 + p];
  float sy = (float)(ho - 1 + kh) + dy;
  float sx = (float)(p - 1 + kw) + dx;
  float fy = floorf(sy), fx = floorf(sx);
  int y0 = (int)fy, x0 = (int)fx;
  float wy = sy - fy, wx = sx - fx;
#pragma unroll
  for (int cy = 0; cy < 2; ++cy) {
#pragma unroll
    for (int cx = 0; cx < 2; ++cx) {
      int y = y0 + cy, xx = x0 + cx;
      float wgt = (cy ? wy : 1.f - wy) * (cx ? wx : 1.f - wx) * mm;
      bool v = ((unsigned)y < 64u) && ((unsigned)xx < 64u);
      wgt = v ? wgt : 0.f;
      int yc = min(max(y, 0), 63), xc = min(max(xx, 0), 63);
      cw[cy * 2 + cx] = wgt;
      cpo[cy * 2 + cx] = ((yc << 6) + xc) * 256;
    }
  }
}

// ---------------- FUSED deform-im2col + GEMM, register-A, M-SPLIT 2 blocks/CU
// Block: 512 thr = 8 waves; grid 512 -> TWO blocks per CU, each its own
// barrier domain. Block mh owns couts [mh*128, mh*128+128): the co-resident
// blocks write fully DISJOINT output rows (no cross-block line interaction,
// unlike r2's nh-split). While one block sits in its __syncthreads vmcnt
// drain (the measured ~75% stall), the other's waves compute -- TLP across
// barrier domains, with the verified r3/r6 sync protocol unchanged
// (__syncthreads only, no inline asm, distance-1 dnv, AF double-buffered).
// Per-wave structure identical to r6 (32x32 tiles: wm in [0,4), wn in {0,1}).
// Gather threads now cover 8 channels (p=tid>>3, cgh=tid&7): one uint4 per
// corner. Blend math and per-output accumulation order unchanged -> output
// bit-identical to r3/r6. XCD swizzle keeps both mh blocks of a (b,ho) on
// one XCD; one b per XCD -> 2MB xt slice L2-resident.
__global__ __launch_bounds__(512, 4) void k_fused(const uint16_t* __restrict__ xt,
                                                  const uint16_t* __restrict__ wt2,
                                                  const float* __restrict__ off,
                                                  const float* __restrict__ msk,
                                                  const float* __restrict__ bias,
                                                  float* __restrict__ out) {
  __shared__ __align__(16) uint16_t Bs[2][64][64];  // 16 KB [buf][pos][k], swizzled
  __shared__ float s_off[18 * 64];
  __shared__ float s_msk[9 * 64];

  int tid = threadIdx.x;
  // bijective for 512; consecutive bids spread over XCDs; within an XCD the
  // mh=0/1 pair of each (b,ho) is adjacent, and b is constant per XCD.
  int swz = ((int)blockIdx.x & 7) * 64 + ((int)blockIdx.x >> 3);
  int b = swz >> 7, ho = (swz >> 1) & 63, mh = swz & 1;

  const float* offb = off + (size_t)b * 18 * 4096 + ho * 64;
  for (int i = tid; i < 18 * 64; i += 512)
    s_off[i] = offb[(size_t)(i >> 6) * 4096 + (i & 63)];
  const float* mskb = msk + (size_t)b * 9 * 4096 + ho * 64;
  for (int i = tid; i < 9 * 64; i += 512)
    s_msk[i] = mskb[(size_t)(i >> 6) * 4096 + (i & 63)];

  int lane = tid & 63, wv = tid >> 6;
  int wm = wv >> 1, wn = wv & 1;            // 4 M-tiles x 2 N-tiles of 32x32
  int q = lane >> 4, r = lane & 15;
  int p = tid >> 3, cgh = tid & 7;          // gather: pos p (0..63), 8-ch chunk
  const uint16_t* xtb = xt + (size_t)b * 1048576 + cgh * 8;
  int bcol = (cgh ^ (p & 7)) << 3;          // swizzled u16 col (16B chunk)
  int awb = (mh * 4 + wm) * 2048;           // A-fragment base within a tap-slab

  f32x4 acc[2][2];
#pragma unroll
  for (int mi = 0; mi < 2; ++mi)
#pragma unroll
    for (int ni = 0; ni < 2; ++ni) acc[mi][ni] = f32x4{0.f, 0.f, 0.f, 0.f};

  __syncthreads();  // off/msk staged

  float cw[4];
  int cpo[4];
  uint4 dnv[4];
  bf16x8 AFA[2][2], AFB[2][2];   // [mi][kh]

  int c0 = (q ^ (r & 7)) << 3;   // swizzled u16 col, kh=0 fragment
  int c1 = c0 ^ 32;              // kh=1
  int rb0 = (wn * 32 + r) * 64;  // ni=0 row offset (u16); ni=1 adds 1024

  // ---- prologue: issue dnv(0) + AF(0); blend(0) -> Bs[0]
  mk_corners(0, p, ho, s_off, s_msk, cw, cpo);
#pragma unroll
  for (int c = 0; c < 4; ++c) dnv[c] = *(const uint4*)(xtb + cpo[c]);
  {
    const uint16_t* wp = wt2 + awb + lane * 8;
    AFA[0][0] = *(const bf16x8*)(wp);
    AFA[0][1] = *(const bf16x8*)(wp + 512);
    AFA[1][0] = *(const bf16x8*)(wp + 1024);
    AFA[1][1] = *(const bf16x8*)(wp + 1536);
  }
  {
    f32x2 f0 = {0.f, 0.f}, f1 = {0.f, 0.f}, f2 = {0.f, 0.f}, f3 = {0.f, 0.f};
#pragma unroll
    for (int c = 0; c < 4; ++c) {
      f32x2 wc = {cw[c], cw[c]};
      f0 += wc * f32x2{b2f_lo(dnv[c].x), b2f_hi(dnv[c].x)};
      f1 += wc * f32x2{b2f_lo(dnv[c].y), b2f_hi(dnv[c].y)};
      f2 += wc * f32x2{b2f_lo(dnv[c].z), b2f_hi(dnv[c].z)};
      f3 += wc * f32x2{b2f_lo(dnv[c].w), b2f_hi(dnv[c].w)};
    }
    uint4 o;
    o.x = pk_bf16(f0.x, f0.y);
    o.y = pk_bf16(f1.x, f1.y);
    o.z = pk_bf16(f2.x, f2.y);
    o.w = pk_bf16(f3.x, f3.y);
    *(uint4*)&Bs[0][p][bcol] = o;
  }
  __syncthreads();

#define BODY(I, AFC, AFN, DOMK, DODNV, DOAF, DOBL)                              \
  {                                                                             \
    if (DOMK) mk_corners(((I) + 1) >> 2, p, ho, s_off, s_msk, cw, cpo);         \
    if (DODNV) {                                                                \
      const int chw = (((I) + 1) & 3) << 6;                                     \
      dnv[0] = *(const uint4*)(xtb + cpo[0] + chw);                             \
      dnv[1] = *(const uint4*)(xtb + cpo[1] + chw);                             \
      dnv[2] = *(const uint4*)(xtb + cpo[2] + chw);                             \
      dnv[3] = *(const uint4*)(xtb + cpo[3] + chw);                             \
    }                                                                           \
    if (DOAF) {                                                                 \
      const uint16_t* wp = wt2 + (size_t)((I) + 1) * 16384 + awb + lane * 8;    \
      AFN[0][0] = *(const bf16x8*)(wp);                                         \
      AFN[0][1] = *(const bf16x8*)(wp + 512);                                   \
      AFN[1][0] = *(const bf16x8*)(wp + 1024);                                  \
      AFN[1][1] = *(const bf16x8*)(wp + 1536);                                  \
    }                                                                           \
    {                                                                           \
      const uint16_t* bsrow = &Bs[(I) & 1][0][0];                               \
      bf16x8 b00 = *(const bf16x8*)(bsrow + rb0 + c0);          /* ni=0 kh=0 */ \
      bf16x8 b01 = *(const bf16x8*)(bsrow + rb0 + c1);          /* ni=0 kh=1 */ \
      bf16x8 b10 = *(const bf16x8*)(bsrow + rb0 + 1024 + c0);   /* ni=1 kh=0 */ \
      bf16x8 b11 = *(const bf16x8*)(bsrow + rb0 + 1024 + c1);   /* ni=1 kh=1 */ \
      __builtin_amdgcn_s_setprio(1);                                            \
      acc[0][0] = __builtin_amdgcn_mfma_f32_16x16x32_bf16(AFC[0][0], b00, acc[0][0], 0, 0, 0); \
      acc[0][1] = __builtin_amdgcn_mfma_f32_16x16x32_bf16(AFC[0][0], b10, acc[0][1], 0, 0, 0); \
      acc[1][0] = __builtin_amdgcn_mfma_f32_16x16x32_bf16(AFC[1][0], b00, acc[1][0], 0, 0, 0); \
      acc[1][1] = __builtin_amdgcn_mfma_f32_16x16x32_bf16(AFC[1][0], b10, acc[1][1], 0, 0, 0); \
      acc[0][0] = __builtin_amdgcn_mfma_f32_16x16x32_bf16(AFC[0][1], b01, acc[0][0], 0, 0, 0); \
      acc[0][1] = __builtin_amdgcn_mfma_f32_16x16x32_bf16(AFC[0][1], b11, acc[0][1], 0, 0, 0); \
      acc[1][0] = __builtin_amdgcn_mfma_f32_16x16x32_bf16(AFC[1][1], b01, acc[1][0], 0, 0, 0); \
      acc[1][1] = __builtin_amdgcn_mfma_f32_16x16x32_bf16(AFC[1][1], b11, acc[1][1], 0, 0, 0); \
      __builtin_amdgcn_s_setprio(0);                                            \
    }                                                                           \
    if (DOBL) {                                                                 \
      f32x2 f0 = {0.f, 0.f}, f1 = {0.f, 0.f}, f2 = {0.f, 0.f}, f3 = {0.f, 0.f};\
      _Pragma("unroll")                                                         \
      for (int c = 0; c < 4; ++c) {                                             \
        f32x2 wc = {cw[c], cw[c]};                                              \
        f0 += wc * f32x2{b2f_lo(dnv[c].x), b2f_hi(dnv[c].x)};                   \
        f1 += wc * f32x2{b2f_lo(dnv[c].y), b2f_hi(dnv[c].y)};                   \
        f2 += wc * f32x2{b2f_lo(dnv[c].z), b2f_hi(dnv[c].z)};                   \
        f3 += wc * f32x2{b2f_lo(dnv[c].w), b2f_hi(dnv[c].w)};                   \
      }                                                                         \
      uint4 o;                                                                  \
      o.x = pk_bf16(f0.x, f0.y);                                                \
      o.y = pk_bf16(f1.x, f1.y);                                                \
      o.z = pk_bf16(f2.x, f2.y);                                                \
      o.w = pk_bf16(f3.x, f3.y);                                                \
      *(uint4*)&Bs[((I) + 1) & 1][p][bcol] = o;                                 \
    }                                                                           \
    __syncthreads();                                                            \
  }

  // main loop: i = 0..31; mk_corners fires when (i+1)%4 == 0
#pragma unroll 1
  for (int ii = 0; ii < 8; ++ii) {
    int i0 = 4 * ii;
    BODY(i0 + 0, AFA, AFB, 0, 1, 1, 1)
    BODY(i0 + 1, AFB, AFA, 0, 1, 1, 1)
    BODY(i0 + 2, AFA, AFB, 0, 1, 1, 1)
    BODY(i0 + 3, AFB, AFA, 1, 1, 1, 1)
  }
  // tail: i = 32..35 (tap 8)
  BODY(32, AFA, AFB, 0, 1, 1, 1)
  BODY(33, AFB, AFA, 0, 1, 1, 1)
  BODY(34, AFA, AFB, 0, 1, 1, 1)
  BODY(35, AFB, AFA, 0, 0, 0, 0)
#undef BODY

  // epilogue: C/D layout col(n) = lane&15 = r, row(m) = q*4 + j
#pragma unroll
  for (int mi = 0; mi < 2; ++mi) {
#pragma unroll
    for (int j = 0; j < 4; ++j) {
      int m = mh * 128 + wm * 32 + mi * 16 + q * 4 + j;
      float bv = bias[m];
#pragma unroll
      for (int ni = 0; ni < 2; ++ni) {
        int wog = wn * 32 + ni * 16 + r;
        out[((size_t)(b * 256 + m)) * 4096 + ho * 64 + wog] = acc[mi][ni][j] + bv;
      }
    }
  }
}

extern "C" void kernel_launch(void* const* d_in, const int* in_sizes, int n_in,
                              void* d_out, int out_size, void* d_ws, size_t ws_size,
                              hipStream_t stream) {
  (void)in_sizes; (void)n_in; (void)out_size; (void)ws_size;
  const float* x      = (const float*)d_in[0];  // [4][256][64][64]
  const float* offset = (const float*)d_in[1];  // [4][18][64][64]
  const float* mask   = (const float*)d_in[2];  // [4][9][64][64]
  const float* weight = (const float*)d_in[3];  // [256][256][3][3]
  const float* bias   = (const float*)d_in[4];  // [256]
  float* out = (float*)d_out;                   // [4][256][64][64]

  uint8_t* ws = (uint8_t*)d_ws;
  uint16_t* xt  = (uint16_t*)ws;                // 8,388,608 B : NHWC bf16
  uint16_t* wt2 = (uint16_t*)(ws + 8388608);    // 1,179,648 B : fragment-linear

  k_prep<<<dim3(2304), 256, 0, stream>>>(x, xt, weight, wt2);
  k_fused<<<dim3(512), 512, 0, stream>>>(xt, wt2, offset, mask, bias, out);
}

// Round 9
// 124.349 us; speedup vs baseline: 1.3434x; 1.0335x over previous
//
#include <hip/hip_runtime.h>
#include <hip/hip_bf16.h>
#include <stdint.h>

// Problem constants: B=4, CIN=COUT=256, H=W=64, 3x3, pad=1, stride=1, dil=1
#define KDIM 2304   // CIN * 9, GEMM K

typedef __bf16 bf16_t;
typedef bf16_t bf16x8 __attribute__((ext_vector_type(8)));
typedef float f32x4 __attribute__((ext_vector_type(4)));
typedef float f32x2 __attribute__((ext_vector_type(2)));

__device__ __forceinline__ float b2f_lo(uint32_t u) {
  union { uint32_t i; float f; } c; c.i = u << 16; return c.f;
}
__device__ __forceinline__ float b2f_hi(uint32_t u) {
  union { uint32_t i; float f; } c; c.i = u & 0xffff0000u; return c.f;
}
__device__ __forceinline__ uint32_t pk_bf16(float a, float b) {
  __hip_bfloat162 h = __float22bfloat162_rn(make_float2(a, b));
  union { __hip_bfloat162 h; uint32_t u; } c; c.h = h; return c.u;
}

// ---------------- merged prep kernel (unchanged from r6/r7 — verified)
// blocks [0,2048): x [4][256][64][64] f32 -> xt [4][64][64][256] bf16 (NHWC)
// blocks [2048,2304): one cout row each: weight -> wt2 fragment-linear bf16:
//   wt2[i(36)][slot(2048)][8], slot = strip*128 + kh*64 + lane,
//   element = w[row=strip*16+(lane&15)][cin=(i&3)*64+kh*32+(lane>>4)*8+e][tap=i>>2]
__global__ __launch_bounds__(256) void k_prep(const float* __restrict__ x,
                                              uint16_t* __restrict__ xt,
                                              const float* __restrict__ w,
                                              uint16_t* __restrict__ wt2) {
  int tid = threadIdx.x;
  if (blockIdx.x < 2048) {
    __shared__ float tile[32][65];
    int b = blockIdx.x >> 9;
    int cgrp = (blockIdx.x >> 6) & 7;
    int sgrp = blockIdx.x & 63;
    int c0 = cgrp << 5, s0 = sgrp << 6;
#pragma unroll
    for (int it = 0; it < 2; ++it) {
      int f = tid + it * 256;
      int rr = f >> 4, col = (f & 15) << 2;
      float4 v = *(const float4*)&x[((size_t)(b * 256 + c0 + rr)) * 4096 + s0 + col];
      tile[rr][col + 0] = v.x;
      tile[rr][col + 1] = v.y;
      tile[rr][col + 2] = v.z;
      tile[rr][col + 3] = v.w;
    }
    __syncthreads();
    int sp = tid >> 2, cg = tid & 3;
    uint4 o;
    o.x = pk_bf16(tile[cg * 8 + 0][sp], tile[cg * 8 + 1][sp]);
    o.y = pk_bf16(tile[cg * 8 + 2][sp], tile[cg * 8 + 3][sp]);
    o.z = pk_bf16(tile[cg * 8 + 4][sp], tile[cg * 8 + 5][sp]);
    o.w = pk_bf16(tile[cg * 8 + 6][sp], tile[cg * 8 + 7][sp]);
    *(uint4*)&xt[((size_t)b * 4096 + s0 + sp) * 256 + c0 + cg * 8] = o;
  } else {
    __shared__ float wl[2304];
    int row = blockIdx.x - 2048;
    const float* wrow = w + (size_t)row * KDIM;
    for (int i2 = tid; i2 < 2304; i2 += 256) wl[i2] = wrow[i2];
    __syncthreads();
    int strip = row >> 4, r16 = row & 15;
    for (int c = tid; c < 288; c += 256) {   // c = tap*32 + w64*8 + kh*4 + seg
      int tap = c >> 5, rem = c & 31;
      int w64 = rem >> 3, kh = (rem >> 2) & 1, seg = rem & 3;
      int i = tap * 4 + w64;
      int cin0 = w64 * 64 + kh * 32 + seg * 8;
      int lanex = seg * 16 + r16;
      uint16_t* dst = wt2 + (size_t)i * 16384 + (size_t)(strip * 128 + kh * 64 + lanex) * 8;
      uint4 o;
      o.x = pk_bf16(wl[(cin0 + 0) * 9 + tap], wl[(cin0 + 1) * 9 + tap]);
      o.y = pk_bf16(wl[(cin0 + 2) * 9 + tap], wl[(cin0 + 3) * 9 + tap]);
      o.z = pk_bf16(wl[(cin0 + 4) * 9 + tap], wl[(cin0 + 5) * 9 + tap]);
      o.w = pk_bf16(wl[(cin0 + 6) * 9 + tap], wl[(cin0 + 7) * 9 + tap]);
      *(uint4*)dst = o;
    }
  }
}

// per-thread bilinear corner setup for one tap (full 64-position row, wo = p)
__device__ __forceinline__ void mk_corners(int tap, int p, int ho,
                                           const float* s_off, const float* s_msk,
                                           float cw[4], int cpo[4]) {
  int kh = tap / 3, kw = tap - kh * 3;
  float dy = s_off[(2 * tap) * 64 + p];
  float dx = s_off[(2 * tap + 1) * 64 + p];
  float mm = s_msk[tap * 64 + p];
  float sy = (float)(ho - 1 + kh) + dy;
  float sx = (float)(p - 1 + kw) + dx;
  float fy = floorf(sy), fx = floorf(sx);
  int y0 = (int)fy, x0 = (int)fx;
  float wy = sy - fy, wx = sx - fx;
#pragma unroll
  for (int cy = 0; cy < 2; ++cy) {
#pragma unroll
    for (int cx = 0; cx < 2; ++cx) {
      int y = y0 + cy, xx = x0 + cx;
      float wgt = (cy ? wy : 1.f - wy) * (cx ? wx : 1.f - wx) * mm;
      bool v = ((unsigned)y < 64u) && ((unsigned)xx < 64u);
      wgt = v ? wgt : 0.f;
      int yc = min(max(y, 0), 63), xc = min(max(xx, 0), 63);
      cw[cy * 2 + cx] = wgt;
      cpo[cy * 2 + cx] = ((yc << 6) + xc) * 256;
    }
  }
}

// ---------------- FUSED deform-im2col + GEMM, register-A, BK=128 (18 bodies)
// Block: 1024 thr = 16 waves (4/SIMD), grid 256 = 1 block/CU. BM=256, BN=64.
// r3/r6/r7 proved the wall is per-body fixed cost (barrier + vmcnt drain +
// issue serialization ~1700cy), invariant to tiling/prefetch/block-count.
// Fix: merge slab pairs (2j,2j+1) -- SAME tap -- into one K=128 body: 18
// barriers instead of 36, corners computed once per pair, blend split over
// 1024 threads in ONE block (r7's mh-duplication removed). Sync protocol
// unchanged (__syncthreads only, distance-1 gather, no inline asm); per-acc
// slab/kh accumulation order preserved -> output bit-identical to r7.
// A (weight) single-buffered in-body from L2-resident wt2 (~100 VGPR total).
__global__ __launch_bounds__(1024, 4) void k_fused(const uint16_t* __restrict__ xt,
                                                   const uint16_t* __restrict__ wt2,
                                                   const float* __restrict__ off,
                                                   const float* __restrict__ msk,
                                                   const float* __restrict__ bias,
                                                   float* __restrict__ out) {
  __shared__ __align__(16) uint16_t Bs[2][64][128];  // 32 KB [buf][pos][k], swizzled
  __shared__ float s_off[18 * 64];
  __shared__ float s_msk[9 * 64];

  int tid = threadIdx.x;
  int swz = ((int)blockIdx.x & 7) * 32 + ((int)blockIdx.x >> 3);
  int b = swz >> 6, ho = swz & 63;

  const float* offb = off + (size_t)b * 18 * 4096 + ho * 64;
  for (int i = tid; i < 18 * 64; i += 1024)
    s_off[i] = offb[(size_t)(i >> 6) * 4096 + (i & 63)];
  const float* mskb = msk + (size_t)b * 9 * 4096 + ho * 64;
  for (int i = tid; i < 9 * 64; i += 1024)
    s_msk[i] = mskb[(size_t)(i >> 6) * 4096 + (i & 63)];

  int lane = tid & 63, wv = tid >> 6;
  int wm = wv >> 1, wn = wv & 1;            // 8 M-tiles x 2 N-tiles of 32x32
  int q = lane >> 4, r = lane & 15;
  // gather: pos p (0..63), 16 chunks of 8ch across the K=128 pair
  int p = tid >> 4, cg16 = tid & 15;
  int half = cg16 >> 3, cg = cg16 & 7;      // half selects slab of the pair
  const uint16_t* xtb = xt + (size_t)b * 1048576 + cg * 8;
  int wcol = (((half << 3) | (cg ^ (p & 7))) << 3);  // swizzled u16 col in 128-row

  f32x4 acc[2][2];
#pragma unroll
  for (int mi = 0; mi < 2; ++mi)
#pragma unroll
    for (int ni = 0; ni < 2; ++ni) acc[mi][ni] = f32x4{0.f, 0.f, 0.f, 0.f};

  __syncthreads();  // off/msk staged

  float cw[4];
  int cpo[4];
  uint4 dnv[4];
  bf16x8 AF0[2][2], AF1[2][2];   // [mi][kh] for slab 2I and 2I+1 (in-body)

  int c0 = (q ^ (r & 7)) << 3;   // swizzled u16 col, kh=0 fragment
  int c1 = c0 ^ 32;              // kh=1 (chunk ^ 4)
  int rowb0 = (wn * 32 + r) * 128;   // ni=0 row base (u16); ni=1 adds 2048

  // ---- prologue: corners(tap0); gather body0 (slabs 0,1); blend -> Bs[0]
  mk_corners(0, p, ho, s_off, s_msk, cw, cpo);
  {
    const int chw = half << 6;   // w64 = half for body 0
#pragma unroll
    for (int c = 0; c < 4; ++c) dnv[c] = *(const uint4*)(xtb + cpo[c] + chw);
  }
  {
    f32x2 f0 = {0.f, 0.f}, f1 = {0.f, 0.f}, f2 = {0.f, 0.f}, f3 = {0.f, 0.f};
#pragma unroll
    for (int c = 0; c < 4; ++c) {
      f32x2 wc = {cw[c], cw[c]};
      f0 += wc * f32x2{b2f_lo(dnv[c].x), b2f_hi(dnv[c].x)};
      f1 += wc * f32x2{b2f_lo(dnv[c].y), b2f_hi(dnv[c].y)};
      f2 += wc * f32x2{b2f_lo(dnv[c].z), b2f_hi(dnv[c].z)};
      f3 += wc * f32x2{b2f_lo(dnv[c].w), b2f_hi(dnv[c].w)};
    }
    uint4 o;
    o.x = pk_bf16(f0.x, f0.y);
    o.y = pk_bf16(f1.x, f1.y);
    o.z = pk_bf16(f2.x, f2.y);
    o.w = pk_bf16(f3.x, f3.y);
    *(uint4*)&Bs[0][p][wcol] = o;
  }
  __syncthreads();

#define BODY(I, DOMK, DODNV, DOAF, DOBL)                                        \
  {                                                                             \
    if (DOMK) mk_corners(((I) + 1) >> 1, p, ho, s_off, s_msk, cw, cpo);         \
    if (DODNV) {                                                                \
      const int chw = (((2 * ((I) + 1)) + half) & 3) << 6;                      \
      dnv[0] = *(const uint4*)(xtb + cpo[0] + chw);                             \
      dnv[1] = *(const uint4*)(xtb + cpo[1] + chw);                             \
      dnv[2] = *(const uint4*)(xtb + cpo[2] + chw);                             \
      dnv[3] = *(const uint4*)(xtb + cpo[3] + chw);                             \
    }                                                                           \
    if (DOAF) {                                                                 \
      const uint16_t* wp = wt2 + (size_t)(2 * (I)) * 16384 + wm * 2048 + lane * 8; \
      AF0[0][0] = *(const bf16x8*)(wp);                                         \
      AF0[0][1] = *(const bf16x8*)(wp + 512);                                   \
      AF0[1][0] = *(const bf16x8*)(wp + 1024);                                  \
      AF0[1][1] = *(const bf16x8*)(wp + 1536);                                  \
      AF1[0][0] = *(const bf16x8*)(wp + 16384);                                 \
      AF1[0][1] = *(const bf16x8*)(wp + 16384 + 512);                           \
      AF1[1][0] = *(const bf16x8*)(wp + 16384 + 1024);                          \
      AF1[1][1] = *(const bf16x8*)(wp + 16384 + 1536);                          \
    }                                                                           \
    {                                                                           \
      const uint16_t* bsrow = &Bs[(I) & 1][0][0];                               \
      bf16x8 bh0n0k0 = *(const bf16x8*)(bsrow + rowb0 + c0);                    \
      bf16x8 bh0n0k1 = *(const bf16x8*)(bsrow + rowb0 + c1);                    \
      bf16x8 bh0n1k0 = *(const bf16x8*)(bsrow + rowb0 + 2048 + c0);             \
      bf16x8 bh0n1k1 = *(const bf16x8*)(bsrow + rowb0 + 2048 + c1);             \
      bf16x8 bh1n0k0 = *(const bf16x8*)(bsrow + rowb0 + 64 + c0);               \
      bf16x8 bh1n0k1 = *(const bf16x8*)(bsrow + rowb0 + 64 + c1);               \
      bf16x8 bh1n1k0 = *(const bf16x8*)(bsrow + rowb0 + 2048 + 64 + c0);        \
      bf16x8 bh1n1k1 = *(const bf16x8*)(bsrow + rowb0 + 2048 + 64 + c1);        \
      __builtin_amdgcn_s_setprio(1);                                            \
      acc[0][0] = __builtin_amdgcn_mfma_f32_16x16x32_bf16(AF0[0][0], bh0n0k0, acc[0][0], 0, 0, 0); \
      acc[0][1] = __builtin_amdgcn_mfma_f32_16x16x32_bf16(AF0[0][0], bh0n1k0, acc[0][1], 0, 0, 0); \
      acc[1][0] = __builtin_amdgcn_mfma_f32_16x16x32_bf16(AF0[1][0], bh0n0k0, acc[1][0], 0, 0, 0); \
      acc[1][1] = __builtin_amdgcn_mfma_f32_16x16x32_bf16(AF0[1][0], bh0n1k0, acc[1][1], 0, 0, 0); \
      acc[0][0] = __builtin_amdgcn_mfma_f32_16x16x32_bf16(AF0[0][1], bh0n0k1, acc[0][0], 0, 0, 0); \
      acc[0][1] = __builtin_amdgcn_mfma_f32_16x16x32_bf16(AF0[0][1], bh0n1k1, acc[0][1], 0, 0, 0); \
      acc[1][0] = __builtin_amdgcn_mfma_f32_16x16x32_bf16(AF0[1][1], bh0n0k1, acc[1][0], 0, 0, 0); \
      acc[1][1] = __builtin_amdgcn_mfma_f32_16x16x32_bf16(AF0[1][1], bh0n1k1, acc[1][1], 0, 0, 0); \
      acc[0][0] = __builtin_amdgcn_mfma_f32_16x16x32_bf16(AF1[0][0], bh1n0k0, acc[0][0], 0, 0, 0); \
      acc[0][1] = __builtin_amdgcn_mfma_f32_16x16x32_bf16(AF1[0][0], bh1n1k0, acc[0][1], 0, 0, 0); \
      acc[1][0] = __builtin_amdgcn_mfma_f32_16x16x32_bf16(AF1[1][0], bh1n0k0, acc[1][0], 0, 0, 0); \
      acc[1][1] = __builtin_amdgcn_mfma_f32_16x16x32_bf16(AF1[1][0], bh1n1k0, acc[1][1], 0, 0, 0); \
      acc[0][0] = __builtin_amdgcn_mfma_f32_16x16x32_bf16(AF1[0][1], bh1n0k1, acc[0][0], 0, 0, 0); \
      acc[0][1] = __builtin_amdgcn_mfma_f32_16x16x32_bf16(AF1[0][1], bh1n1k1, acc[0][1], 0, 0, 0); \
      acc[1][0] = __builtin_amdgcn_mfma_f32_16x16x32_bf16(AF1[1][1], bh1n0k1, acc[1][0], 0, 0, 0); \
      acc[1][1] = __builtin_amdgcn_mfma_f32_16x16x32_bf16(AF1[1][1], bh1n1k1, acc[1][1], 0, 0, 0); \
      __builtin_amdgcn_s_setprio(0);                                            \
    }                                                                           \
    if (DOBL) {                                                                 \
      f32x2 f0 = {0.f, 0.f}, f1 = {0.f, 0.f}, f2 = {0.f, 0.f}, f3 = {0.f, 0.f};\
      _Pragma("unroll")                                                         \
      for (int c = 0; c < 4; ++c) {                                             \
        f32x2 wc = {cw[c], cw[c]};                                              \
        f0 += wc * f32x2{b2f_lo(dnv[c].x), b2f_hi(dnv[c].x)};                   \
        f1 += wc * f32x2{b2f_lo(dnv[c].y), b2f_hi(dnv[c].y)};                   \
        f2 += wc * f32x2{b2f_lo(dnv[c].z), b2f_hi(dnv[c].z)};                   \
        f3 += wc * f32x2{b2f_lo(dnv[c].w), b2f_hi(dnv[c].w)};                   \
      }                                                                         \
      uint4 o;                                                                  \
      o.x = pk_bf16(f0.x, f0.y);                                                \
      o.y = pk_bf16(f1.x, f1.y);                                                \
      o.z = pk_bf16(f2.x, f2.y);                                                \
      o.w = pk_bf16(f3.x, f3.y);                                                \
      *(uint4*)&Bs[((I) + 1) & 1][p][wcol] = o;                                 \
    }                                                                           \
    __syncthreads();                                                            \
  }

  // 18 bodies; corners recomputed when next body starts a new tap (I odd)
#pragma unroll 1
  for (int ii = 0; ii < 8; ++ii) {
    BODY(2 * ii + 0, 0, 1, 1, 1)
    BODY(2 * ii + 1, 1, 1, 1, 1)
  }
  BODY(16, 0, 1, 1, 1)
  BODY(17, 0, 0, 1, 0)
#undef BODY

  // epilogue: C/D layout col(n) = lane&15 = r, row(m) = q*4 + j
#pragma unroll
  for (int mi = 0; mi < 2; ++mi) {
#pragma unroll
    for (int j = 0; j < 4; ++j) {
      int m = wm * 32 + mi * 16 + q * 4 + j;
      float bv = bias[m];
#pragma unroll
      for (int ni = 0; ni < 2; ++ni) {
        int wog = wn * 32 + ni * 16 + r;
        out[((size_t)(b * 256 + m)) * 4096 + ho * 64 + wog] = acc[mi][ni][j] + bv;
      }
    }
  }
}

extern "C" void kernel_launch(void* const* d_in, const int* in_sizes, int n_in,
                              void* d_out, int out_size, void* d_ws, size_t ws_size,
                              hipStream_t stream) {
  (void)in_sizes; (void)n_in; (void)out_size; (void)ws_size;
  const float* x      = (const float*)d_in[0];  // [4][256][64][64]
  const float* offset = (const float*)d_in[1];  // [4][18][64][64]
  const float* mask   = (const float*)d_in[2];  // [4][9][64][64]
  const float* weight = (const float*)d_in[3];  // [256][256][3][3]
  const float* bias   = (const float*)d_in[4];  // [256]
  float* out = (float*)d_out;                   // [4][256][64][64]

  uint8_t* ws = (uint8_t*)d_ws;
  uint16_t* xt  = (uint16_t*)ws;                // 8,388,608 B : NHWC bf16
  uint16_t* wt2 = (uint16_t*)(ws + 8388608);    // 1,179,648 B : fragment-linear

  k_prep<<<dim3(2304), 256, 0, stream>>>(x, xt, weight, wt2);
  k_fused<<<dim3(256), 1024, 0, stream>>>(xt, wt2, offset, mask, bias, out);
}

// Round 10
// 120.575 us; speedup vs baseline: 1.3855x; 1.0313x over previous
//
#include <hip/hip_runtime.h>
#include <hip/hip_bf16.h>
#include <stdint.h>

// Problem constants: B=4, CIN=COUT=256, H=W=64, 3x3, pad=1, stride=1, dil=1
#define KDIM 2304   // CIN * 9, GEMM K

typedef __bf16 bf16_t;
typedef bf16_t bf16x8 __attribute__((ext_vector_type(8)));
typedef float f32x4 __attribute__((ext_vector_type(4)));
typedef float f32x2 __attribute__((ext_vector_type(2)));

__device__ __forceinline__ float b2f_lo(uint32_t u) {
  union { uint32_t i; float f; } c; c.i = u << 16; return c.f;
}
__device__ __forceinline__ float b2f_hi(uint32_t u) {
  union { uint32_t i; float f; } c; c.i = u & 0xffff0000u; return c.f;
}
__device__ __forceinline__ uint32_t pk_bf16(float a, float b) {
  __hip_bfloat162 h = __float22bfloat162_rn(make_float2(a, b));
  union { __hip_bfloat162 h; uint32_t u; } c; c.h = h; return c.u;
}

// ---------------- merged prep kernel
// blocks [0,1024): x [4][256][64][64] f32 -> xt [4][64][64][256] bf16 (NHWC).
// 64ch x 64pos tiles: xt writes are contiguous 128B per position (2 uint4 per
// thread back-to-back) instead of r9's 64B chunks -> full-line HBM writes.
// blocks [1024,1280): one cout row each: weight -> wt2 fragment-linear bf16:
//   wt2[i(36)][slot(2048)][8], slot = strip*128 + kh*64 + lane,
//   element = w[row=strip*16+(lane&15)][cin=(i&3)*64+kh*32+(lane>>4)*8+e][tap=i>>2]
__global__ __launch_bounds__(256) void k_prep(const float* __restrict__ x,
                                              uint16_t* __restrict__ xt,
                                              const float* __restrict__ w,
                                              uint16_t* __restrict__ wt2) {
  int tid = threadIdx.x;
  if (blockIdx.x < 1024) {
    __shared__ float tile[64][65];
    int b = blockIdx.x >> 8;
    int cgrp = (blockIdx.x >> 6) & 3;
    int sgrp = blockIdx.x & 63;
    int c0 = cgrp << 6, s0 = sgrp << 6;
#pragma unroll
    for (int it = 0; it < 4; ++it) {
      int f = tid + it * 256;
      int rr = f >> 4, col = (f & 15) << 2;
      float4 v = *(const float4*)&x[((size_t)(b * 256 + c0 + rr)) * 4096 + s0 + col];
      tile[rr][col + 0] = v.x;
      tile[rr][col + 1] = v.y;
      tile[rr][col + 2] = v.z;
      tile[rr][col + 3] = v.w;
    }
    __syncthreads();
    int sp = tid >> 2, cb = (tid & 3) * 16;
    uint4 o1, o2;
    o1.x = pk_bf16(tile[cb + 0][sp], tile[cb + 1][sp]);
    o1.y = pk_bf16(tile[cb + 2][sp], tile[cb + 3][sp]);
    o1.z = pk_bf16(tile[cb + 4][sp], tile[cb + 5][sp]);
    o1.w = pk_bf16(tile[cb + 6][sp], tile[cb + 7][sp]);
    o2.x = pk_bf16(tile[cb + 8][sp], tile[cb + 9][sp]);
    o2.y = pk_bf16(tile[cb + 10][sp], tile[cb + 11][sp]);
    o2.z = pk_bf16(tile[cb + 12][sp], tile[cb + 13][sp]);
    o2.w = pk_bf16(tile[cb + 14][sp], tile[cb + 15][sp]);
    uint16_t* dst = &xt[((size_t)(b * 4096 + s0 + sp)) * 256 + c0 + cb];
    *(uint4*)dst = o1;
    *(uint4*)(dst + 8) = o2;
  } else {
    __shared__ float wl[2304];
    int row = blockIdx.x - 1024;
    const float* wrow = w + (size_t)row * KDIM;
    for (int i2 = tid; i2 < 2304; i2 += 256) wl[i2] = wrow[i2];
    __syncthreads();
    int strip = row >> 4, r16 = row & 15;
    for (int c = tid; c < 288; c += 256) {   // c = tap*32 + w64*8 + kh*4 + seg
      int tap = c >> 5, rem = c & 31;
      int w64 = rem >> 3, kh = (rem >> 2) & 1, seg = rem & 3;
      int i = tap * 4 + w64;
      int cin0 = w64 * 64 + kh * 32 + seg * 8;
      int lanex = seg * 16 + r16;
      uint16_t* dst = wt2 + (size_t)i * 16384 + (size_t)(strip * 128 + kh * 64 + lanex) * 8;
      uint4 o;
      o.x = pk_bf16(wl[(cin0 + 0) * 9 + tap], wl[(cin0 + 1) * 9 + tap]);
      o.y = pk_bf16(wl[(cin0 + 2) * 9 + tap], wl[(cin0 + 3) * 9 + tap]);
      o.z = pk_bf16(wl[(cin0 + 4) * 9 + tap], wl[(cin0 + 5) * 9 + tap]);
      o.w = pk_bf16(wl[(cin0 + 6) * 9 + tap], wl[(cin0 + 7) * 9 + tap]);
      *(uint4*)dst = o;
    }
  }
}

// per-thread bilinear corner setup for one tap (full 64-position row, wo = p)
__device__ __forceinline__ void mk_corners(int tap, int p, int ho,
                                           const float* s_off, const float* s_msk,
                                           float cw[4], int cpo[4]) {
  int kh = tap / 3, kw = tap - kh * 3;
  float dy = s_off[(2 * tap) * 64 + p];
  float dx = s_off[(2 * tap + 1) * 64 + p];
  float mm = s_msk[tap * 64 + p];
  float sy = (float)(ho - 1 + kh) + dy;
  float sx = (float)(p - 1 + kw) + dx;
  float fy = floorf(sy), fx = floorf(sx);
  int y0 = (int)fy, x0 = (int)fx;
  float wy = sy - fy, wx = sx - fx;
#pragma unroll
  for (int cy = 0; cy < 2; ++cy) {
#pragma unroll
    for (int cx = 0; cx < 2; ++cx) {
      int y = y0 + cy, xx = x0 + cx;
      float wgt = (cy ? wy : 1.f - wy) * (cx ? wx : 1.f - wx) * mm;
      bool v = ((unsigned)y < 64u) && ((unsigned)xx < 64u);
      wgt = v ? wgt : 0.f;
      int yc = min(max(y, 0), 63), xc = min(max(xx, 0), 63);
      cw[cy * 2 + cx] = wgt;
      cpo[cy * 2 + cx] = ((yc << 6) + xc) * 256;
    }
  }
}

// ---------------- FUSED deform-im2col + GEMM, register-A, BK=128, de-spilled
// Block: 1024 thr = 16 waves (4/SIMD), grid 256 = 1 block/CU. BM=256, BN=64.
// 18 barriers (r9-verified BK=128 amortization, +6us). r9's regression fixed:
// each body is TWO sequential K=64 phases (slab 2I then 2I+1), each loading
// only 4 A-frags + 4 B-frags at a time; a sched_barrier(0) between the
// phase-0 MFMA cluster and phase-1 loads stops the scheduler hoisting phase-1
// loads into phase 0 (the r9 spill: WRITE 25.6MB/FETCH 14.6MB scratch).
// sched_barrier is a pure compile-time fence (no memory semantics) -- safe,
// unlike r4's asm-waitcnt protocol. Per-acc MFMA order unchanged from r9 ->
// output bit-identical. Sync = __syncthreads only.
__global__ __launch_bounds__(1024, 4) void k_fused(const uint16_t* __restrict__ xt,
                                                   const uint16_t* __restrict__ wt2,
                                                   const float* __restrict__ off,
                                                   const float* __restrict__ msk,
                                                   const float* __restrict__ bias,
                                                   float* __restrict__ out) {
  __shared__ __align__(16) uint16_t Bs[2][64][128];  // 32 KB [buf][pos][k], swizzled
  __shared__ float s_off[18 * 64];
  __shared__ float s_msk[9 * 64];

  int tid = threadIdx.x;
  int swz = ((int)blockIdx.x & 7) * 32 + ((int)blockIdx.x >> 3);
  int b = swz >> 6, ho = swz & 63;

  const float* offb = off + (size_t)b * 18 * 4096 + ho * 64;
  for (int i = tid; i < 18 * 64; i += 1024)
    s_off[i] = offb[(size_t)(i >> 6) * 4096 + (i & 63)];
  const float* mskb = msk + (size_t)b * 9 * 4096 + ho * 64;
  for (int i = tid; i < 9 * 64; i += 1024)
    s_msk[i] = mskb[(size_t)(i >> 6) * 4096 + (i & 63)];

  int lane = tid & 63, wv = tid >> 6;
  int wm = wv >> 1, wn = wv & 1;            // 8 M-tiles x 2 N-tiles of 32x32
  int q = lane >> 4, r = lane & 15;
  // gather: pos p (0..63), 16 chunks of 8ch across the K=128 pair
  int p = tid >> 4, cg16 = tid & 15;
  int half = cg16 >> 3, cg = cg16 & 7;      // half selects slab of the pair
  const uint16_t* xtb = xt + (size_t)b * 1048576 + cg * 8;
  int wcol = (((half << 3) | (cg ^ (p & 7))) << 3);  // swizzled u16 col in 128-row

  f32x4 acc[2][2];
#pragma unroll
  for (int mi = 0; mi < 2; ++mi)
#pragma unroll
    for (int ni = 0; ni < 2; ++ni) acc[mi][ni] = f32x4{0.f, 0.f, 0.f, 0.f};

  __syncthreads();  // off/msk staged

  float cw[4];
  int cpo[4];
  uint4 dnv[4];

  int c0 = (q ^ (r & 7)) << 3;   // swizzled u16 col, kh=0 fragment
  int c1 = c0 ^ 32;              // kh=1 (chunk ^ 4)
  int rowb0 = (wn * 32 + r) * 128;   // ni=0 row base (u16); ni=1 adds 2048

  // ---- prologue: corners(tap0); gather body0 (slabs 0,1); blend -> Bs[0]
  mk_corners(0, p, ho, s_off, s_msk, cw, cpo);
  {
    const int chw = half << 6;   // w64 = half for body 0
#pragma unroll
    for (int c = 0; c < 4; ++c) dnv[c] = *(const uint4*)(xtb + cpo[c] + chw);
  }
  {
    f32x2 f0 = {0.f, 0.f}, f1 = {0.f, 0.f}, f2 = {0.f, 0.f}, f3 = {0.f, 0.f};
#pragma unroll
    for (int c = 0; c < 4; ++c) {
      f32x2 wc = {cw[c], cw[c]};
      f0 += wc * f32x2{b2f_lo(dnv[c].x), b2f_hi(dnv[c].x)};
      f1 += wc * f32x2{b2f_lo(dnv[c].y), b2f_hi(dnv[c].y)};
      f2 += wc * f32x2{b2f_lo(dnv[c].z), b2f_hi(dnv[c].z)};
      f3 += wc * f32x2{b2f_lo(dnv[c].w), b2f_hi(dnv[c].w)};
    }
    uint4 o;
    o.x = pk_bf16(f0.x, f0.y);
    o.y = pk_bf16(f1.x, f1.y);
    o.z = pk_bf16(f2.x, f2.y);
    o.w = pk_bf16(f3.x, f3.y);
    *(uint4*)&Bs[0][p][wcol] = o;
  }
  __syncthreads();

#define PHASE(AOFS, BOFS)                                                       \
    {                                                                           \
      bf16x8 a00 = *(const bf16x8*)(wp + (AOFS));                               \
      bf16x8 a01 = *(const bf16x8*)(wp + (AOFS) + 512);                         \
      bf16x8 a10 = *(const bf16x8*)(wp + (AOFS) + 1024);                        \
      bf16x8 a11 = *(const bf16x8*)(wp + (AOFS) + 1536);                        \
      bf16x8 b0k0 = *(const bf16x8*)(bsrow + rowb0 + (BOFS) + c0);              \
      bf16x8 b0k1 = *(const bf16x8*)(bsrow + rowb0 + (BOFS) + c1);              \
      bf16x8 b1k0 = *(const bf16x8*)(bsrow + rowb0 + 2048 + (BOFS) + c0);       \
      bf16x8 b1k1 = *(const bf16x8*)(bsrow + rowb0 + 2048 + (BOFS) + c1);       \
      __builtin_amdgcn_s_setprio(1);                                            \
      acc[0][0] = __builtin_amdgcn_mfma_f32_16x16x32_bf16(a00, b0k0, acc[0][0], 0, 0, 0); \
      acc[0][1] = __builtin_amdgcn_mfma_f32_16x16x32_bf16(a00, b1k0, acc[0][1], 0, 0, 0); \
      acc[1][0] = __builtin_amdgcn_mfma_f32_16x16x32_bf16(a10, b0k0, acc[1][0], 0, 0, 0); \
      acc[1][1] = __builtin_amdgcn_mfma_f32_16x16x32_bf16(a10, b1k0, acc[1][1], 0, 0, 0); \
      acc[0][0] = __builtin_amdgcn_mfma_f32_16x16x32_bf16(a01, b0k1, acc[0][0], 0, 0, 0); \
      acc[0][1] = __builtin_amdgcn_mfma_f32_16x16x32_bf16(a01, b1k1, acc[0][1], 0, 0, 0); \
      acc[1][0] = __builtin_amdgcn_mfma_f32_16x16x32_bf16(a11, b0k1, acc[1][0], 0, 0, 0); \
      acc[1][1] = __builtin_amdgcn_mfma_f32_16x16x32_bf16(a11, b1k1, acc[1][1], 0, 0, 0); \
      __builtin_amdgcn_s_setprio(0);                                            \
    }

#define BODY(I, DOMK, DODNV, DOBL)                                              \
  {                                                                             \
    if (DOMK) mk_corners(((I) + 1) >> 1, p, ho, s_off, s_msk, cw, cpo);         \
    if (DODNV) {                                                                \
      const int chw = (((2 * ((I) + 1)) + half) & 3) << 6;                      \
      dnv[0] = *(const uint4*)(xtb + cpo[0] + chw);                             \
      dnv[1] = *(const uint4*)(xtb + cpo[1] + chw);                             \
      dnv[2] = *(const uint4*)(xtb + cpo[2] + chw);                             \
      dnv[3] = *(const uint4*)(xtb + cpo[3] + chw);                             \
    }                                                                           \
    const uint16_t* wp = wt2 + (size_t)(2 * (I)) * 16384 + wm * 2048 + lane * 8;\
    const uint16_t* bsrow = &Bs[(I) & 1][0][0];                                 \
    PHASE(0, 0)                                 /* slab 2I   (cols 0..7)  */    \
    __builtin_amdgcn_sched_barrier(0);          /* keep phase 1 loads below */  \
    PHASE(16384, 64)                            /* slab 2I+1 (cols 8..15) */    \
    if (DOBL) {                                                                 \
      f32x2 f0 = {0.f, 0.f}, f1 = {0.f, 0.f}, f2 = {0.f, 0.f}, f3 = {0.f, 0.f};\
      _Pragma("unroll")                                                         \
      for (int c = 0; c < 4; ++c) {                                             \
        f32x2 wc = {cw[c], cw[c]};                                              \
        f0 += wc * f32x2{b2f_lo(dnv[c].x), b2f_hi(dnv[c].x)};                   \
        f1 += wc * f32x2{b2f_lo(dnv[c].y), b2f_hi(dnv[c].y)};                   \
        f2 += wc * f32x2{b2f_lo(dnv[c].z), b2f_hi(dnv[c].z)};                   \
        f3 += wc * f32x2{b2f_lo(dnv[c].w), b2f_hi(dnv[c].w)};                   \
      }                                                                         \
      uint4 o;                                                                  \
      o.x = pk_bf16(f0.x, f0.y);                                                \
      o.y = pk_bf16(f1.x, f1.y);                                                \
      o.z = pk_bf16(f2.x, f2.y);                                                \
      o.w = pk_bf16(f3.x, f3.y);                                                \
      *(uint4*)&Bs[((I) + 1) & 1][p][wcol] = o;                                 \
    }                                                                           \
    __syncthreads();                                                            \
  }

  // 18 bodies; corners recomputed when the next body starts a new tap (I odd)
#pragma unroll 1
  for (int ii = 0; ii < 8; ++ii) {
    BODY(2 * ii + 0, 0, 1, 1)
    BODY(2 * ii + 1, 1, 1, 1)
  }
  BODY(16, 0, 1, 1)
  BODY(17, 0, 0, 0)
#undef BODY
#undef PHASE

  // epilogue: C/D layout col(n) = lane&15 = r, row(m) = q*4 + j
#pragma unroll
  for (int mi = 0; mi < 2; ++mi) {
#pragma unroll
    for (int j = 0; j < 4; ++j) {
      int m = wm * 32 + mi * 16 + q * 4 + j;
      float bv = bias[m];
#pragma unroll
      for (int ni = 0; ni < 2; ++ni) {
        int wog = wn * 32 + ni * 16 + r;
        out[((size_t)(b * 256 + m)) * 4096 + ho * 64 + wog] = acc[mi][ni][j] + bv;
      }
    }
  }
}

extern "C" void kernel_launch(void* const* d_in, const int* in_sizes, int n_in,
                              void* d_out, int out_size, void* d_ws, size_t ws_size,
                              hipStream_t stream) {
  (void)in_sizes; (void)n_in; (void)out_size; (void)ws_size;
  const float* x      = (const float*)d_in[0];  // [4][256][64][64]
  const float* offset = (const float*)d_in[1];  // [4][18][64][64]
  const float* mask   = (const float*)d_in[2];  // [4][9][64][64]
  const float* weight = (const float*)d_in[3];  // [256][256][3][3]
  const float* bias   = (const float*)d_in[4];  // [256]
  float* out = (float*)d_out;                   // [4][256][64][64]

  uint8_t* ws = (uint8_t*)d_ws;
  uint16_t* xt  = (uint16_t*)ws;                // 8,388,608 B : NHWC bf16
  uint16_t* wt2 = (uint16_t*)(ws + 8388608);    // 1,179,648 B : fragment-linear

  k_prep<<<dim3(1280), 256, 0, stream>>>(x, xt, weight, wt2);
  k_fused<<<dim3(256), 1024, 0, stream>>>(xt, wt2, offset, mask, bias, out);
}

// Round 11
// 118.968 us; speedup vs baseline: 1.4042x; 1.0135x over previous
//
#include <hip/hip_runtime.h>
#include <hip/hip_bf16.h>
#include <stdint.h>

// Problem constants: B=4, CIN=COUT=256, H=W=64, 3x3, pad=1, stride=1, dil=1
#define KDIM 2304   // CIN * 9, GEMM K

typedef __bf16 bf16_t;
typedef bf16_t bf16x8 __attribute__((ext_vector_type(8)));
typedef float f32x4 __attribute__((ext_vector_type(4)));
typedef float f32x2 __attribute__((ext_vector_type(2)));

__device__ __forceinline__ float b2f_lo(uint32_t u) {
  union { uint32_t i; float f; } c; c.i = u << 16; return c.f;
}
__device__ __forceinline__ float b2f_hi(uint32_t u) {
  union { uint32_t i; float f; } c; c.i = u & 0xffff0000u; return c.f;
}
__device__ __forceinline__ uint32_t pk_bf16(float a, float b) {
  __hip_bfloat162 h = __float22bfloat162_rn(make_float2(a, b));
  union { __hip_bfloat162 h; uint32_t u; } c; c.h = h; return c.u;
}

// blend 4 corners (8 ch each) -> packed bf16x8 (r0-verified math)
__device__ __forceinline__ uint4 blend8(const uint4 d[4], const float cw[4]) {
  f32x2 f0 = {0.f, 0.f}, f1 = {0.f, 0.f}, f2 = {0.f, 0.f}, f3 = {0.f, 0.f};
#pragma unroll
  for (int c = 0; c < 4; ++c) {
    f32x2 wc = {cw[c], cw[c]};
    f0 += wc * f32x2{b2f_lo(d[c].x), b2f_hi(d[c].x)};
    f1 += wc * f32x2{b2f_lo(d[c].y), b2f_hi(d[c].y)};
    f2 += wc * f32x2{b2f_lo(d[c].z), b2f_hi(d[c].z)};
    f3 += wc * f32x2{b2f_lo(d[c].w), b2f_hi(d[c].w)};
  }
  uint4 o;
  o.x = pk_bf16(f0.x, f0.y);
  o.y = pk_bf16(f1.x, f1.y);
  o.z = pk_bf16(f2.x, f2.y);
  o.w = pk_bf16(f3.x, f3.y);
  return o;
}

// ---------------- merged prep kernel (r10-verified)
// blocks [0,1024): x [4][256][64][64] f32 -> xt [4][64][64][256] bf16 (NHWC).
// blocks [1024,1280): one cout row each: weight -> wt2 fragment-linear bf16:
//   wt2[i(36)][slot(2048)][8], slot = strip*128 + kh*64 + lane,
//   element = w[row=strip*16+(lane&15)][cin=(i&3)*64+kh*32+(lane>>4)*8+e][tap=i>>2]
__global__ __launch_bounds__(256) void k_prep(const float* __restrict__ x,
                                              uint16_t* __restrict__ xt,
                                              const float* __restrict__ w,
                                              uint16_t* __restrict__ wt2) {
  int tid = threadIdx.x;
  if (blockIdx.x < 1024) {
    __shared__ float tile[64][65];
    int b = blockIdx.x >> 8;
    int cgrp = (blockIdx.x >> 6) & 3;
    int sgrp = blockIdx.x & 63;
    int c0 = cgrp << 6, s0 = sgrp << 6;
#pragma unroll
    for (int it = 0; it < 4; ++it) {
      int f = tid + it * 256;
      int rr = f >> 4, col = (f & 15) << 2;
      float4 v = *(const float4*)&x[((size_t)(b * 256 + c0 + rr)) * 4096 + s0 + col];
      tile[rr][col + 0] = v.x;
      tile[rr][col + 1] = v.y;
      tile[rr][col + 2] = v.z;
      tile[rr][col + 3] = v.w;
    }
    __syncthreads();
    int sp = tid >> 2, cb = (tid & 3) * 16;
    uint4 o1, o2;
    o1.x = pk_bf16(tile[cb + 0][sp], tile[cb + 1][sp]);
    o1.y = pk_bf16(tile[cb + 2][sp], tile[cb + 3][sp]);
    o1.z = pk_bf16(tile[cb + 4][sp], tile[cb + 5][sp]);
    o1.w = pk_bf16(tile[cb + 6][sp], tile[cb + 7][sp]);
    o2.x = pk_bf16(tile[cb + 8][sp], tile[cb + 9][sp]);
    o2.y = pk_bf16(tile[cb + 10][sp], tile[cb + 11][sp]);
    o2.z = pk_bf16(tile[cb + 12][sp], tile[cb + 13][sp]);
    o2.w = pk_bf16(tile[cb + 14][sp], tile[cb + 15][sp]);
    uint16_t* dst = &xt[((size_t)(b * 4096 + s0 + sp)) * 256 + c0 + cb];
    *(uint4*)dst = o1;
    *(uint4*)(dst + 8) = o2;
  } else {
    __shared__ float wl[2304];
    int row = blockIdx.x - 1024;
    const float* wrow = w + (size_t)row * KDIM;
    for (int i2 = tid; i2 < 2304; i2 += 256) wl[i2] = wrow[i2];
    __syncthreads();
    int strip = row >> 4, r16 = row & 15;
    for (int c = tid; c < 288; c += 256) {   // c = tap*32 + w64*8 + kh*4 + seg
      int tap = c >> 5, rem = c & 31;
      int w64 = rem >> 3, kh = (rem >> 2) & 1, seg = rem & 3;
      int i = tap * 4 + w64;
      int cin0 = w64 * 64 + kh * 32 + seg * 8;
      int lanex = seg * 16 + r16;
      uint16_t* dst = wt2 + (size_t)i * 16384 + (size_t)(strip * 128 + kh * 64 + lanex) * 8;
      uint4 o;
      o.x = pk_bf16(wl[(cin0 + 0) * 9 + tap], wl[(cin0 + 1) * 9 + tap]);
      o.y = pk_bf16(wl[(cin0 + 2) * 9 + tap], wl[(cin0 + 3) * 9 + tap]);
      o.z = pk_bf16(wl[(cin0 + 4) * 9 + tap], wl[(cin0 + 5) * 9 + tap]);
      o.w = pk_bf16(wl[(cin0 + 6) * 9 + tap], wl[(cin0 + 7) * 9 + tap]);
      *(uint4*)dst = o;
    }
  }
}

// per-thread bilinear corner setup for one tap (full 64-position row, wo = p)
__device__ __forceinline__ void mk_corners(int tap, int p, int ho,
                                           const float* s_off, const float* s_msk,
                                           float cw[4], int cpo[4]) {
  int kh = tap / 3, kw = tap - kh * 3;
  float dy = s_off[(2 * tap) * 64 + p];
  float dx = s_off[(2 * tap + 1) * 64 + p];
  float mm = s_msk[tap * 64 + p];
  float sy = (float)(ho - 1 + kh) + dy;
  float sx = (float)(p - 1 + kw) + dx;
  float fy = floorf(sy), fx = floorf(sx);
  int y0 = (int)fy, x0 = (int)fx;
  float wy = sy - fy, wx = sx - fx;
#pragma unroll
  for (int cy = 0; cy < 2; ++cy) {
#pragma unroll
    for (int cx = 0; cx < 2; ++cx) {
      int y = y0 + cy, xx = x0 + cx;
      float wgt = (cy ? wy : 1.f - wy) * (cx ? wx : 1.f - wx) * mm;
      bool v = ((unsigned)y < 64u) && ((unsigned)xx < 64u);
      wgt = v ? wgt : 0.f;
      int yc = min(max(y, 0), 63), xc = min(max(xx, 0), 63);
      cw[cy * 2 + cx] = wgt;
      cpo[cy * 2 + cx] = ((yc << 6) + xc) * 256;
    }
  }
}

// ---------------- FUSED deform-im2col + GEMM: BK=256, 9 bodies (1 tap each)
// Block: 1024 thr = 16 waves (4/SIMD), grid 256 = 1 block/CU. BM=256, BN=64.
// Ledger (r3..r10): per-K64-slab work W~2525cy, per-body fixed F~1125cy.
// r9/r10 confirmed amortizing F is THE lever (36->18 bodies = -8.4us net).
// This round: 18->9 bodies (BK=256 = exactly one tap): 9*(F+4W) ~ 101k cy.
// Four self-contained K=64 phases per body, sched_barrier(0) between them
// (r10-verified spill fence; WRITE_SIZE==16384 is the spill sentinel).
// Each thread gathers+blends TWO 8-ch chunks per body (slabs sA, sA+2) --
// total blend work conserved. Bs rows padded +32B (stride 544B) to rotate
// row base banks (attacks r9/r10's 2.36M write-side conflicts); read bank
// pattern re-derived <=2-way (free) under the pad. Slab-ascending/kh-
// ascending per-acc MFMA order preserved -> output bit-identical (absmax
// must be exactly 0.0078125). Sync = __syncthreads only (r3/r6 protocol).
__global__ __launch_bounds__(1024, 4) void k_fused(const uint16_t* __restrict__ xt,
                                                   const uint16_t* __restrict__ wt2,
                                                   const float* __restrict__ off,
                                                   const float* __restrict__ msk,
                                                   const float* __restrict__ bias,
                                                   float* __restrict__ out) {
  constexpr int ROWU = 272;            // 256 + 16 u16 pad -> 544 B row stride
  constexpr int BUFU = 64 * ROWU;      // 17408 u16 per buffer
  __shared__ __align__(16) uint16_t Bs[2 * BUFU];   // 69632 B
  __shared__ float s_off[18 * 64];
  __shared__ float s_msk[9 * 64];

  int tid = threadIdx.x;
  int swz = ((int)blockIdx.x & 7) * 32 + ((int)blockIdx.x >> 3);
  int b = swz >> 6, ho = swz & 63;

  const float* offb = off + (size_t)b * 18 * 4096 + ho * 64;
  for (int i = tid; i < 18 * 64; i += 1024)
    s_off[i] = offb[(size_t)(i >> 6) * 4096 + (i & 63)];
  const float* mskb = msk + (size_t)b * 9 * 4096 + ho * 64;
  for (int i = tid; i < 9 * 64; i += 1024)
    s_msk[i] = mskb[(size_t)(i >> 6) * 4096 + (i & 63)];

  int lane = tid & 63, wv = tid >> 6;
  int wm = wv >> 1, wn = wv & 1;            // 8 M-tiles x 2 N-tiles of 32x32
  int q = lane >> 4, r = lane & 15;
  // gather: pos p (0..63), chunk-pair: thread covers slab sA and sA+2, 8ch each
  int p = tid >> 4, cg16 = tid & 15;
  int sA = cg16 >> 3, cg = cg16 & 7;
  const uint16_t* xtb = xt + (size_t)b * 1048576 + cg * 8;
  int chwA = sA * 64, chwB = chwA + 128;    // channel offsets (u16) of the 2 slabs
  int ch = cg ^ (p & 7);                    // XOR-swizzled 16B chunk within slab
  int wcolA = p * ROWU + sA * 64 + ch * 8;  // flat u16 offset within a buffer
  int wcolB = wcolA + 128;

  f32x4 acc[2][2];
#pragma unroll
  for (int mi = 0; mi < 2; ++mi)
#pragma unroll
    for (int ni = 0; ni < 2; ++ni) acc[mi][ni] = f32x4{0.f, 0.f, 0.f, 0.f};

  __syncthreads();  // off/msk staged

  float cw[4];
  int cpo[4];
  uint4 dnvA[4], dnvB[4];

  int c0 = (q ^ (r & 7)) << 3;       // swizzled u16 col, kh=0 fragment
  int c1 = c0 ^ 32;                  // kh=1 (chunk ^ 4)
  int rowb0 = (wn * 32 + r) * ROWU;  // ni=0 row base (u16); ni=1 adds 16*ROWU

  // ---- prologue: corners(tap0); gather both chunks; blend -> Bs[0]
  mk_corners(0, p, ho, s_off, s_msk, cw, cpo);
#pragma unroll
  for (int c = 0; c < 4; ++c) dnvA[c] = *(const uint4*)(xtb + cpo[c] + chwA);
#pragma unroll
  for (int c = 0; c < 4; ++c) dnvB[c] = *(const uint4*)(xtb + cpo[c] + chwB);
  *(uint4*)(Bs + wcolA) = blend8(dnvA, cw);
  *(uint4*)(Bs + wcolB) = blend8(dnvB, cw);
  __syncthreads();

#define PHASE(S)                                                                \
    {                                                                           \
      const uint16_t* wp = wpb + (S) * 16384;                                   \
      bf16x8 a00 = *(const bf16x8*)(wp);          /* mi0 kh0 */                 \
      bf16x8 a01 = *(const bf16x8*)(wp + 512);    /* mi0 kh1 */                 \
      bf16x8 a10 = *(const bf16x8*)(wp + 1024);   /* mi1 kh0 */                 \
      bf16x8 a11 = *(const bf16x8*)(wp + 1536);   /* mi1 kh1 */                 \
      const uint16_t* br = bsrow + rowb0 + (S) * 64;                            \
      bf16x8 b0k0 = *(const bf16x8*)(br + c0);                                  \
      bf16x8 b0k1 = *(const bf16x8*)(br + c1);                                  \
      bf16x8 b1k0 = *(const bf16x8*)(br + 16 * ROWU + c0);                      \
      bf16x8 b1k1 = *(const bf16x8*)(br + 16 * ROWU + c1);                      \
      __builtin_amdgcn_s_setprio(1);                                            \
      acc[0][0] = __builtin_amdgcn_mfma_f32_16x16x32_bf16(a00, b0k0, acc[0][0], 0, 0, 0); \
      acc[0][1] = __builtin_amdgcn_mfma_f32_16x16x32_bf16(a00, b1k0, acc[0][1], 0, 0, 0); \
      acc[1][0] = __builtin_amdgcn_mfma_f32_16x16x32_bf16(a10, b0k0, acc[1][0], 0, 0, 0); \
      acc[1][1] = __builtin_amdgcn_mfma_f32_16x16x32_bf16(a10, b1k0, acc[1][1], 0, 0, 0); \
      acc[0][0] = __builtin_amdgcn_mfma_f32_16x16x32_bf16(a01, b0k1, acc[0][0], 0, 0, 0); \
      acc[0][1] = __builtin_amdgcn_mfma_f32_16x16x32_bf16(a01, b1k1, acc[0][1], 0, 0, 0); \
      acc[1][0] = __builtin_amdgcn_mfma_f32_16x16x32_bf16(a11, b0k1, acc[1][0], 0, 0, 0); \
      acc[1][1] = __builtin_amdgcn_mfma_f32_16x16x32_bf16(a11, b1k1, acc[1][1], 0, 0, 0); \
      __builtin_amdgcn_s_setprio(0);                                            \
    }

  // 9 bodies, one tap each; body i reads Bs[i&1], blends tap i+1 into Bs[(i+1)&1]
#pragma unroll 1
  for (int i = 0; i < 9; ++i) {
    if (i < 8) {
      mk_corners(i + 1, p, ho, s_off, s_msk, cw, cpo);
#pragma unroll
      for (int c = 0; c < 4; ++c) dnvA[c] = *(const uint4*)(xtb + cpo[c] + chwA);
#pragma unroll
      for (int c = 0; c < 4; ++c) dnvB[c] = *(const uint4*)(xtb + cpo[c] + chwB);
    }
    const uint16_t* wpb = wt2 + (size_t)(4 * i) * 16384 + wm * 2048 + lane * 8;
    const uint16_t* bsrow = Bs + (i & 1) * BUFU;
    PHASE(0)
    __builtin_amdgcn_sched_barrier(0);
    PHASE(1)
    __builtin_amdgcn_sched_barrier(0);
    PHASE(2)
    __builtin_amdgcn_sched_barrier(0);
    PHASE(3)
    if (i < 8) {
      uint16_t* wdst = Bs + ((i + 1) & 1) * BUFU;
      *(uint4*)(wdst + wcolA) = blend8(dnvA, cw);
      *(uint4*)(wdst + wcolB) = blend8(dnvB, cw);
    }
    __syncthreads();
  }
#undef PHASE

  // epilogue: C/D layout col(n) = lane&15 = r, row(m) = q*4 + j
#pragma unroll
  for (int mi = 0; mi < 2; ++mi) {
#pragma unroll
    for (int j = 0; j < 4; ++j) {
      int m = wm * 32 + mi * 16 + q * 4 + j;
      float bv = bias[m];
#pragma unroll
      for (int ni = 0; ni < 2; ++ni) {
        int wog = wn * 32 + ni * 16 + r;
        out[((size_t)(b * 256 + m)) * 4096 + ho * 64 + wog] = acc[mi][ni][j] + bv;
      }
    }
  }
}

extern "C" void kernel_launch(void* const* d_in, const int* in_sizes, int n_in,
                              void* d_out, int out_size, void* d_ws, size_t ws_size,
                              hipStream_t stream) {
  (void)in_sizes; (void)n_in; (void)out_size; (void)ws_size;
  const float* x      = (const float*)d_in[0];  // [4][256][64][64]
  const float* offset = (const float*)d_in[1];  // [4][18][64][64]
  const float* mask   = (const float*)d_in[2];  // [4][9][64][64]
  const float* weight = (const float*)d_in[3];  // [256][256][3][3]
  const float* bias   = (const float*)d_in[4];  // [256]
  float* out = (float*)d_out;                   // [4][256][64][64]

  uint8_t* ws = (uint8_t*)d_ws;
  uint16_t* xt  = (uint16_t*)ws;                // 8,388,608 B : NHWC bf16
  uint16_t* wt2 = (uint16_t*)(ws + 8388608);    // 1,179,648 B : fragment-linear

  k_prep<<<dim3(1280), 256, 0, stream>>>(x, xt, weight, wt2);
  k_fused<<<dim3(256), 1024, 0, stream>>>(xt, wt2, offset, mask, bias, out);
}